// Round 15
// baseline (1215.518 us; speedup 1.0000x reference)
//
#include <hip/hip_runtime.h>
#include <hip/hip_bf16.h>

typedef __hip_bfloat16 bf16;
typedef __attribute__((ext_vector_type(8))) short short8v;
typedef __attribute__((ext_vector_type(4))) float float4v;

#define N_NODES 10000
#define E_EDGES 160000

__device__ __forceinline__ float b2f(bf16 v){ return __bfloat162float(v); }
__device__ __forceinline__ bf16 f2b(float v){ return __float2bfloat16(v); }

union U8 { int4 v; bf16 h[8]; };
union U4 { int2 v; bf16 h[4]; };

// ---- dtype-flexible external accessors (flag: 1 = bf16, 0 = f32) ----------
__device__ __forceinline__ float ldx(const void* p, size_t i, bool isb){
    return isb ? b2f(((const bf16*)p)[i]) : ((const float*)p)[i];
}
__device__ __forceinline__ void ld8(const void* p, size_t i, bool isb, float* o){
    if (isb) {
        U8 u; u.v = *reinterpret_cast<const int4*>((const bf16*)p + i);
        #pragma unroll
        for (int j = 0; j < 8; j++) o[j] = b2f(u.h[j]);
    } else {
        const float4* q = reinterpret_cast<const float4*>((const float*)p + i);
        float4 a = q[0], b = q[1];
        o[0]=a.x; o[1]=a.y; o[2]=a.z; o[3]=a.w; o[4]=b.x; o[5]=b.y; o[6]=b.z; o[7]=b.w;
    }
}
__device__ __forceinline__ void stx(void* p, size_t i, bool isb, float v){
    if (isb) ((bf16*)p)[i] = f2b(v); else ((float*)p)[i] = v;
}

// async global->LDS, 16 B/lane (HW: LDS dest = wave-uniform base + lane*16)
typedef const __attribute__((address_space(1))) void* gas_p;
typedef __attribute__((address_space(3))) void* las_p;
__device__ __forceinline__ void gl16(const bf16* g, bf16* l){
    __builtin_amdgcn_global_load_lds((gas_p)g, (las_p)l, 16, 0, 0);
}

// 4x4 in-register transpose across 4 lanes (verified r9-r14):
// input: a[r] = M[r][t] (t = lane&3); output: a[u] = M[t][u]
__device__ __forceinline__ void quadT(float* a, int t){
    float x0 = (t & 1) ? a[0] : a[1];
    float y0 = __shfl_xor(x0, 1);
    if (t & 1) a[0] = y0; else a[1] = y0;
    float x1 = (t & 1) ? a[2] : a[3];
    float y1 = __shfl_xor(x1, 1);
    if (t & 1) a[2] = y1; else a[3] = y1;
    float x2 = (t & 2) ? a[0] : a[2];
    float y2 = __shfl_xor(x2, 2);
    if (t & 2) a[0] = y2; else a[2] = y2;
    float x3 = (t & 2) ? a[1] : a[3];
    float y3 = __shfl_xor(x3, 2);
    if (t & 2) a[1] = y3; else a[3] = y3;
}

// XCD-bijective swizzle of a linear workgroup id
__device__ __forceinline__ int xcd_swz(int wg, int nwg){
    const int q = nwg >> 3, r = nwg & 7;
    const int xcd = wg & 7, ix = wg >> 3;
    return (xcd < r ? xcd * (q + 1) : r * (q + 1) + (xcd - r) * q) + ix;
}

// ---------------------------------------------------------------------------
__global__ void detect_dtype(const unsigned short* __restrict__ xw, int* __restrict__ flag){
    const int lane = threadIdx.x;  // 64 threads
    int cnt = 0;
    for (int i = lane; i < 8192; i += 64) {
        const unsigned e = (xw[i] >> 7) & 0xFF;
        if (e == 0 || (e >= 100 && e <= 140)) cnt++;
    }
    #pragma unroll
    for (int off = 32; off >= 1; off >>= 1) cnt += __shfl_xor(cnt, off);
    if (lane == 0) *flag = (cnt >= 6554) ? 1 : 0;
}

__global__ __launch_bounds__(256) void cvt_bf16(
    const void* __restrict__ in, bf16* __restrict__ out, long n8, const int* __restrict__ dflag)
{
    const bool isb = (*dflag != 0);
    const long t = (long)blockIdx.x * 256 + threadIdx.x;
    if (t >= n8) return;
    float f[8]; ld8(in, (size_t)t * 8, isb, f);
    U8 u;
    #pragma unroll
    for (int j = 0; j < 8; j++) u.h[j] = f2b(f[j]);
    *reinterpret_cast<int4*>(&out[t * 8]) = u.v;
}

// pack W[K,Nmat] -> Wt[Nmat][K] bf16
__global__ __launch_bounds__(256) void pack_wT(
    const void* __restrict__ W, bf16* __restrict__ out,
    int K, int Nmat, const int* __restrict__ dflag)
{
    const bool isb = (*dflag != 0);
    const int idx = blockIdx.x * 256 + threadIdx.x;
    if (idx >= K * Nmat) return;
    const int k = idx / Nmat, n = idx - k * Nmat;
    out[(size_t)n * K + k] = f2b(ldx(W, idx, isb));
}

// ---------------------------------------------------------------------------
// MFMA GEMM v7 (verified r10-r14): BK=64 single-buffer + quadT epilogue.
// BM=BN=128, 4 waves 2x2.
// MODE 0: node QKV (Bt0|1|2 segmented NC=768; bias on col<256)
// MODE 7: edge QKV fused (seg0 -> C=QE +bias+xg[sidx]; seg1 -> C2=KVE.k;
//         seg2 -> C2=KVE.v +xg[didx])
// ---------------------------------------------------------------------------
template<int MODE>
__global__ __launch_bounds__(256) void mg(
    const bf16* __restrict__ A, int M, int K, int NC,
    const bf16* __restrict__ Bt0, const bf16* __restrict__ Bt1, const bf16* __restrict__ Bt2,
    const void* __restrict__ bias,
    const bf16* __restrict__ xg,
    const int* __restrict__ sidx, const int* __restrict__ didx,
    bf16* __restrict__ C, bf16* __restrict__ C2,
    const int* __restrict__ dflag)
{
    const bool isb = (*dflag != 0);
    __shared__ __align__(16) bf16 Al[128 * 64];
    __shared__ __align__(16) bf16 Bl[128 * 64];
    __shared__ float biasl[128];

    const int tid = threadIdx.x;
    const int lane = tid & 63, wave = tid >> 6;
    const int l15 = lane & 15, g = lane >> 4;
    const int t4 = l15 & 3, qd = l15 >> 2;
    const int wr = wave >> 1, wc = wave & 1;

    const int nwgx = gridDim.x;
    int wg = xcd_swz(blockIdx.y * nwgx + blockIdx.x, nwgx * gridDim.y);
    const int rb = (wg / nwgx) * 128, cb = (wg % nwgx) * 128;

    const bf16* Bsel; int cloc;
    {
        const int seg = cb >> 8;
        Bsel = (seg == 0) ? Bt0 : ((seg == 1) ? Bt1 : Bt2);
        cloc = cb & 255;
    }

    if (tid < 128) {
        float bv = 0.f;
        const int gc = cb + tid;
        if (gc < 256) bv = ldx(bias, gc, isb);
        biasl[tid] = bv;
    }

    const int sp = lane & 7, sr8 = lane >> 3;
    int rls[4]; long arows[4];
    #pragma unroll
    for (int j = 0; j < 4; j++) {
        const int rl = wave * 32 + j * 8 + sr8;
        rls[j] = rl;
        const int gm = rb + rl;
        arows[j] = (gm < M) ? gm : (M - 1);
    }

    float4v acc[4][4];
    #pragma unroll
    for (int i = 0; i < 4; i++)
        #pragma unroll
        for (int j = 0; j < 4; j++)
            acc[i][j] = (float4v){0.f, 0.f, 0.f, 0.f};

    for (int k0 = 0; k0 < K; k0 += 64) {
        #pragma unroll
        for (int j = 0; j < 4; j++) {
            const int rl = rls[j];
            const int pp = sp ^ (rl & 7);
            gl16(A + arows[j] * K + k0 + pp * 8,                 Al + rl * 64 + sp * 8);
            gl16(Bsel + (size_t)(cloc + rl) * K + k0 + pp * 8,   Bl + rl * 64 + sp * 8);
        }
        __syncthreads();
        #pragma unroll
        for (int ks = 0; ks < 2; ks++) {
            short8v av[4], bv[4];
            #pragma unroll
            for (int mi = 0; mi < 4; mi++) {
                const int row = wr * 64 + mi * 16 + l15;
                const int cp = (ks * 4 + g) ^ (row & 7);
                av[mi] = *reinterpret_cast<const short8v*>(&Al[row * 64 + cp * 8]);
            }
            #pragma unroll
            for (int ni = 0; ni < 4; ni++) {
                const int row = wc * 64 + ni * 16 + l15;
                const int cp = (ks * 4 + g) ^ (row & 7);
                bv[ni] = *reinterpret_cast<const short8v*>(&Bl[row * 64 + cp * 8]);
            }
            #pragma unroll
            for (int mi = 0; mi < 4; mi++)
                #pragma unroll
                for (int ni = 0; ni < 4; ni++)
                    acc[mi][ni] = __builtin_amdgcn_mfma_f32_16x16x32_bf16(
                        av[mi], bv[ni], acc[mi][ni], 0, 0, 0);
        }
        __syncthreads();
    }

    #pragma unroll
    for (int mi = 0; mi < 4; mi++) {
        const int grow = rb + wr * 64 + mi * 16 + g * 4 + t4;
        const bool ok = (grow < M);
        int s5 = 0, d5 = 0;
        if (MODE == 7 && ok) {
            if (cb < 256) s5 = sidx[grow];
            else if (cb >= 512) d5 = didx[grow];
        }
        #pragma unroll
        for (int ni = 0; ni < 4; ni++) {
            float a[4];
            #pragma unroll
            for (int r = 0; r < 4; r++) a[r] = acc[mi][ni][r];
            quadT(a, t4);
            if (!ok) continue;
            const int ct = wc * 64 + ni * 16 + qd * 4;
            const int gc = cb + ct;
            if (MODE == 0) {
                if (gc < 256) {
                    #pragma unroll
                    for (int u = 0; u < 4; u++) a[u] += biasl[ct + u];
                }
            }
            if (MODE == 7) {
                if (gc < 256) {
                    U4 xx; xx.v = *reinterpret_cast<const int2*>(&xg[(size_t)s5 * 256 + gc]);
                    #pragma unroll
                    for (int u = 0; u < 4; u++) a[u] += biasl[ct + u] + b2f(xx.h[u]);
                } else if (gc >= 512) {
                    U4 xx; xx.v = *reinterpret_cast<const int2*>(&xg[(size_t)d5 * 256 + (gc - 512)]);
                    #pragma unroll
                    for (int u = 0; u < 4; u++) a[u] += b2f(xx.h[u]);
                }
            }
            U4 o;
            #pragma unroll
            for (int u = 0; u < 4; u++) o.h[u] = f2b(a[u]);
            if (MODE == 7) {
                if (gc < 256) *reinterpret_cast<int2*>(&C[(size_t)grow * 256 + gc]) = o.v;
                else          *reinterpret_cast<int2*>(&C2[(size_t)grow * 512 + (gc - 256)]) = o.v;
            } else {
                *reinterpret_cast<int2*>(&C[(size_t)grow * NC + gc]) = o.v;
            }
        }
    }
}

// ---------------------------------------------------------------------------
// LN-fused GEMM (verified r11-r14): 512 thr, 8 waves (2x4), BM=128, BN=256.
// MODE 8 only here: Wo+bias+resid -> LN -> C bf16.
// ---------------------------------------------------------------------------
__global__ __launch_bounds__(512) void mgln8(
    const bf16* __restrict__ A, int M, int K,
    const bf16* __restrict__ Bt,
    const void* __restrict__ bias,
    const bf16* __restrict__ resid,
    const void* __restrict__ lng, const void* __restrict__ lnb,
    bf16* __restrict__ C,
    const int* __restrict__ dflag)
{
    const bool isb = (*dflag != 0);
    __shared__ __align__(16) bf16 Al[128 * 64];   // 16KB (Ps overlay)
    __shared__ __align__(16) bf16 Bl[256 * 64];   // 32KB (Mr/Rsd overlay)
    __shared__ float biasl[256];
    __shared__ float lngl[256];
    __shared__ float lnbl[256];

    const int tid = threadIdx.x;
    const int lane = tid & 63, wave = tid >> 6;
    const int l15 = lane & 15, g = lane >> 4;
    const int t4 = l15 & 3, qd = l15 >> 2;
    const int wr = wave >> 2, wc = wave & 3;   // 2 x 4 wave grid

    const int wg = xcd_swz(blockIdx.y, gridDim.y);
    const int rb = wg * 128;

    if (tid < 256) {
        biasl[tid] = ldx(bias, tid, isb);
        lngl[tid]  = ldx(lng,  tid, isb);
        lnbl[tid]  = ldx(lnb,  tid, isb);
    }

    const int sp = lane & 7, sr8 = lane >> 3;
    int rlA[2]; long arA[2];
    #pragma unroll
    for (int j = 0; j < 2; j++) {
        const int rl = wave * 16 + j * 8 + sr8;
        rlA[j] = rl;
        const int gm = rb + rl;
        arA[j] = (gm < M) ? gm : (M - 1);
    }
    int rlB[4];
    #pragma unroll
    for (int j = 0; j < 4; j++) rlB[j] = wave * 32 + j * 8 + sr8;

    float4v acc[4][4];
    #pragma unroll
    for (int i = 0; i < 4; i++)
        #pragma unroll
        for (int j = 0; j < 4; j++)
            acc[i][j] = (float4v){0.f, 0.f, 0.f, 0.f};

    for (int k0 = 0; k0 < K; k0 += 64) {
        #pragma unroll
        for (int j = 0; j < 2; j++) {
            const int pp = sp ^ (rlA[j] & 7);
            gl16(A + arA[j] * K + k0 + pp * 8, Al + rlA[j] * 64 + sp * 8);
        }
        #pragma unroll
        for (int j = 0; j < 4; j++) {
            const int pp = sp ^ (rlB[j] & 7);
            gl16(Bt + (size_t)rlB[j] * K + k0 + pp * 8, Bl + rlB[j] * 64 + sp * 8);
        }
        __syncthreads();
        #pragma unroll
        for (int ks = 0; ks < 2; ks++) {
            short8v av[4], bv[4];
            #pragma unroll
            for (int mi = 0; mi < 4; mi++) {
                const int row = wr * 64 + mi * 16 + l15;
                const int cp = (ks * 4 + g) ^ (row & 7);
                av[mi] = *reinterpret_cast<const short8v*>(&Al[row * 64 + cp * 8]);
            }
            #pragma unroll
            for (int ni = 0; ni < 4; ni++) {
                const int row = wc * 64 + ni * 16 + l15;
                const int cp = (ks * 4 + g) ^ (row & 7);
                bv[ni] = *reinterpret_cast<const short8v*>(&Bl[row * 64 + cp * 8]);
            }
            #pragma unroll
            for (int mi = 0; mi < 4; mi++)
                #pragma unroll
                for (int ni = 0; ni < 4; ni++)
                    acc[mi][ni] = __builtin_amdgcn_mfma_f32_16x16x32_bf16(
                        av[mi], bv[ni], acc[mi][ni], 0, 0, 0);
        }
        __syncthreads();
    }

    float s1[4] = {0.f,0.f,0.f,0.f}, s2[4] = {0.f,0.f,0.f,0.f};
    #pragma unroll
    for (int mi = 0; mi < 4; mi++) {
        const int grow = rb + wr * 64 + mi * 16 + g * 4 + t4;
        const bool ok = (grow < M);
        #pragma unroll
        for (int ni = 0; ni < 4; ni++) {
            float a[4];
            #pragma unroll
            for (int r = 0; r < 4; r++) a[r] = acc[mi][ni][r];
            quadT(a, t4);
            const int ct = wc * 64 + ni * 16 + qd * 4;
            U4 rr; rr.v = make_int2(0, 0);
            if (ok) rr.v = *reinterpret_cast<const int2*>(&resid[(size_t)grow * 256 + ct]);
            #pragma unroll
            for (int u = 0; u < 4; u++) {
                a[u] += biasl[ct + u] + b2f(rr.h[u]);
                s1[mi] += a[u];
                s2[mi] += a[u] * a[u];
                acc[mi][ni][u] = a[u];
            }
        }
    }
    float* Ps1 = (float*)Al;          // [16][128]
    float* Ps2 = Ps1 + 2048;
    #pragma unroll
    for (int mi = 0; mi < 4; mi++) {
        const int rowl = wr * 64 + mi * 16 + g * 4 + t4;
        Ps1[(wc * 4 + qd) * 128 + rowl] = s1[mi];
        Ps2[(wc * 4 + qd) * 128 + rowl] = s2[mi];
    }
    __syncthreads();
    float* Mr  = (float*)Bl;
    float* Rsd = Mr + 128;
    if (tid < 128) {
        float a1 = 0.f, a2 = 0.f;
        #pragma unroll
        for (int k = 0; k < 16; k++) { a1 += Ps1[k * 128 + tid]; a2 += Ps2[k * 128 + tid]; }
        const float mn = a1 * (1.f / 256.f);
        const float var = a2 * (1.f / 256.f) - mn * mn;
        Mr[tid] = mn;
        Rsd[tid] = rsqrtf(fmaxf(var, 0.f) + 1e-5f);
    }
    __syncthreads();
    #pragma unroll
    for (int mi = 0; mi < 4; mi++) {
        const int rowl = wr * 64 + mi * 16 + g * 4 + t4;
        const int grow = rb + rowl;
        if (grow >= M) continue;
        const float mn = Mr[rowl], rd = Rsd[rowl];
        #pragma unroll
        for (int ni = 0; ni < 4; ni++) {
            const int ct = wc * 64 + ni * 16 + qd * 4;
            U4 ob;
            #pragma unroll
            for (int u = 0; u < 4; u++)
                ob.h[u] = f2b((acc[mi][ni][u] - mn) * rd * lngl[ct + u] + lnbl[ct + u]);
            *reinterpret_cast<int2*>(&C[(size_t)grow * 256 + ct]) = ob.v;
        }
    }
}

// ---------------------------------------------------------------------------
// mgffn: fused FFN = LN2(H + relu(H@W1+b1)@W2 + b2) -> dtype-flex out.
// 64-row block, 256 thr / 4 waves (1x4 col grid), 48KB LDS (3 blocks/CU).
// H-block staged once in Al[64][256] (swizzled).  8 chunks of the 1024-wide
// intermediate: phase1 (A from Al, W1 frags from global/L2) -> quadT+bias+
// relu -> swizzled Pl[64][128] -> phase2 (A from Pl, W2 frags from global)
// accumulating out.  LN epilogue per mgln; resid read from Al (LDS-hot).
// W1t [1024][256], W2t [256][1024] (pack_wT layouts).
// ---------------------------------------------------------------------------
__global__ __launch_bounds__(256, 3) void mgffn(
    const bf16* __restrict__ H, int M,
    const bf16* __restrict__ W1t, const bf16* __restrict__ W2t,
    const void* __restrict__ b1, const void* __restrict__ b2,
    const void* __restrict__ lng, const void* __restrict__ lnb,
    void* __restrict__ outv, long obase,
    const int* __restrict__ dflag)
{
    const bool isb = (*dflag != 0);
    __shared__ __align__(16) bf16 Al[64 * 256];   // 32KB, resident
    __shared__ __align__(16) bf16 Pl[64 * 128];   // 16KB, per-chunk (Ps overlay)

    const int tid = threadIdx.x;
    const int lane = tid & 63, wave = tid >> 6;
    const int l15 = lane & 15, g = lane >> 4;
    const int t4 = l15 & 3, qd = l15 >> 2;
    const int wc = wave;                       // 1x4 col grid

    const int wg = xcd_swz(blockIdx.y, gridDim.y);
    const int rb = wg * 64;

    // ---- stage Al once: 64 rows x 256 cols, inverse-XOR swizzled source ----
    const int sgr = lane & 31;                 // granule 0..31 (8 elems each)
    const int sr2 = lane >> 5;                 // 0..1
    #pragma unroll
    for (int it = 0; it < 8; it++) {
        const int rl = wave * 16 + (it & 7) * 2 + sr2;
        const long ar = (rb + rl < M) ? (rb + rl) : (M - 1);
        const int pp = sgr ^ (rl & 7);
        gl16(H + ar * 256 + pp * 8, Al + rl * 256 + sgr * 8);
    }
    __syncthreads();

    float4v oacc[4][4];
    #pragma unroll
    for (int i = 0; i < 4; i++)
        #pragma unroll
        for (int j = 0; j < 4; j++)
            oacc[i][j] = (float4v){0.f, 0.f, 0.f, 0.f};

    for (int c = 0; c < 8; c++) {
        // ---- phase 1: P = relu(Al @ W1t[c*128..+128] + b1) ----
        float4v pacc[4][2];
        #pragma unroll
        for (int i = 0; i < 4; i++)
            #pragma unroll
            for (int j = 0; j < 2; j++)
                pacc[i][j] = (float4v){0.f, 0.f, 0.f, 0.f};
        #pragma unroll
        for (int ks = 0; ks < 8; ks++) {
            short8v af[4], bf_[2];
            #pragma unroll
            for (int mi = 0; mi < 4; mi++) {
                const int row = mi * 16 + l15;
                const int cp = (ks * 4 + g) ^ (row & 7);
                af[mi] = *reinterpret_cast<const short8v*>(&Al[row * 256 + cp * 8]);
            }
            #pragma unroll
            for (int ni = 0; ni < 2; ni++) {
                const int n = c * 128 + wc * 32 + ni * 16 + l15;
                bf_[ni] = *reinterpret_cast<const short8v*>(&W1t[(size_t)n * 256 + ks * 32 + g * 8]);
            }
            #pragma unroll
            for (int mi = 0; mi < 4; mi++)
                #pragma unroll
                for (int ni = 0; ni < 2; ni++)
                    pacc[mi][ni] = __builtin_amdgcn_mfma_f32_16x16x32_bf16(
                        af[mi], bf_[ni], pacc[mi][ni], 0, 0, 0);
        }
        __syncthreads();   // prior phase2 reads of Pl complete
        #pragma unroll
        for (int mi = 0; mi < 4; mi++) {
            const int prow = mi * 16 + g * 4 + t4;
            #pragma unroll
            for (int ni = 0; ni < 2; ni++) {
                float a[4];
                #pragma unroll
                for (int r = 0; r < 4; r++) a[r] = pacc[mi][ni][r];
                quadT(a, t4);
                const int pc = wc * 32 + ni * 16 + qd * 4;      // col in chunk
                U4 o;
                #pragma unroll
                for (int u = 0; u < 4; u++)
                    o.h[u] = f2b(fmaxf(a[u] + ldx(b1, c * 128 + pc + u, isb), 0.f));
                const int wgr = (pc >> 3) ^ (prow & 7);
                *reinterpret_cast<int2*>(&Pl[prow * 128 + wgr * 8 + (pc & 7)]) = o.v;
            }
        }
        __syncthreads();
        // ---- phase 2: oacc += Pl @ W2t[:, c*128..+128] ----
        #pragma unroll
        for (int ks = 0; ks < 4; ks++) {
            short8v af2[4], bf2[4];
            #pragma unroll
            for (int mi = 0; mi < 4; mi++) {
                const int row = mi * 16 + l15;
                const int cp = (ks * 4 + g) ^ (row & 7);
                af2[mi] = *reinterpret_cast<const short8v*>(&Pl[row * 128 + cp * 8]);
            }
            #pragma unroll
            for (int ni = 0; ni < 4; ni++) {
                const int n = wc * 64 + ni * 16 + l15;
                bf2[ni] = *reinterpret_cast<const short8v*>(
                    &W2t[(size_t)n * 1024 + c * 128 + ks * 32 + g * 8]);
            }
            #pragma unroll
            for (int mi = 0; mi < 4; mi++)
                #pragma unroll
                for (int ni = 0; ni < 4; ni++)
                    oacc[mi][ni] = __builtin_amdgcn_mfma_f32_16x16x32_bf16(
                        af2[mi], bf2[ni], oacc[mi][ni], 0, 0, 0);
        }
    }
    __syncthreads();

    // ---- LN epilogue: + b2 + resid(Al), rowwise mean/var, scale, store ----
    float s1[4] = {0.f,0.f,0.f,0.f}, s2[4] = {0.f,0.f,0.f,0.f};
    #pragma unroll
    for (int mi = 0; mi < 4; mi++) {
        const int rowl = mi * 16 + g * 4 + t4;
        #pragma unroll
        for (int ni = 0; ni < 4; ni++) {
            float a[4];
            #pragma unroll
            for (int r = 0; r < 4; r++) a[r] = oacc[mi][ni][r];
            quadT(a, t4);
            const int ct = wc * 64 + ni * 16 + qd * 4;
            const int rg = (ct >> 3) ^ (rowl & 7);
            U4 rr; rr.v = *reinterpret_cast<const int2*>(&Al[rowl * 256 + rg * 8 + (ct & 7)]);
            #pragma unroll
            for (int u = 0; u < 4; u++) {
                a[u] += ldx(b2, ct + u, isb) + b2f(rr.h[u]);
                s1[mi] += a[u];
                s2[mi] += a[u] * a[u];
                oacc[mi][ni][u] = a[u];
            }
        }
    }
    float* Ps1 = (float*)Pl;            // [16][64]
    float* Ps2 = Ps1 + 1024;
    float* Mr  = Ps2 + 1024;
    float* Rsd = Mr + 64;
    #pragma unroll
    for (int mi = 0; mi < 4; mi++) {
        const int rowl = mi * 16 + g * 4 + t4;
        Ps1[(wc * 4 + qd) * 64 + rowl] = s1[mi];
        Ps2[(wc * 4 + qd) * 64 + rowl] = s2[mi];
    }
    __syncthreads();
    if (tid < 64) {
        float a1 = 0.f, a2 = 0.f;
        #pragma unroll
        for (int k = 0; k < 16; k++) { a1 += Ps1[k * 64 + tid]; a2 += Ps2[k * 64 + tid]; }
        const float mn = a1 * (1.f / 256.f);
        const float var = a2 * (1.f / 256.f) - mn * mn;
        Mr[tid] = mn;
        Rsd[tid] = rsqrtf(fmaxf(var, 0.f) + 1e-5f);
    }
    __syncthreads();
    #pragma unroll
    for (int mi = 0; mi < 4; mi++) {
        const int rowl = mi * 16 + g * 4 + t4;
        const int grow = rb + rowl;
        if (grow >= M) continue;
        const float mn = Mr[rowl], rd = Rsd[rowl];
        #pragma unroll
        for (int ni = 0; ni < 4; ni++) {
            const int ct = wc * 64 + ni * 16 + qd * 4;
            float o[4];
            #pragma unroll
            for (int u = 0; u < 4; u++)
                o[u] = (oacc[mi][ni][u] - mn) * rd * ldx(lng, ct + u, isb) + ldx(lnb, ct + u, isb);
            if (isb) {
                U4 ob;
                #pragma unroll
                for (int u = 0; u < 4; u++) ob.h[u] = f2b(o[u]);
                *reinterpret_cast<int2*>((bf16*)outv + obase + (size_t)grow * 256 + ct) = ob.v;
            } else {
                float4 f4 = make_float4(o[0], o[1], o[2], o[3]);
                *reinterpret_cast<float4*>((float*)outv + obase + (size_t)grow * 256 + ct) = f4;
            }
        }
    }
}

// ---------------------------------------------------------------------------
// Node attention (vectorized, verified r14): wave per node, lane owns 4 cols.
// ---------------------------------------------------------------------------
__global__ __launch_bounds__(256) void attn_node(
    const bf16* __restrict__ QKV, const int* __restrict__ lsrc,
    const bf16* __restrict__ lgx16, bf16* __restrict__ O)
{
    const int w = threadIdx.x >> 6, lane = threadIdx.x & 63;
    const int d = blockIdx.x * 4 + w;
    if (d >= N_NODES) return;
    const int c4 = lane * 4;
    U4 uq; uq.v = *reinterpret_cast<const int2*>(&QKV[(size_t)d * 768 + c4]);
    float q[4];
    #pragma unroll
    for (int u = 0; u < 4; u++) q[u] = b2f(uq.h[u]);
    float acc[4] = {0.f, 0.f, 0.f, 0.f};
    float z = 0.f;
    for (int j = 0; j < 16; j++) {
        const int i = d + j * N_NODES;
        const int s = lsrc[i];
        U4 ue; ue.v = *reinterpret_cast<const int2*>(&lgx16[(size_t)i * 256 + c4]);
        U4 uk; uk.v = *reinterpret_cast<const int2*>(&QKV[(size_t)s * 768 + 256 + c4]);
        U4 uv; uv.v = *reinterpret_cast<const int2*>(&QKV[(size_t)s * 768 + 512 + c4]);
        float e[4], p = 0.f;
        #pragma unroll
        for (int u = 0; u < 4; u++) {
            e[u] = b2f(ue.h[u]);
            p += (b2f(uk.h[u]) + e[u]) * q[u];
        }
        p += __shfl_xor(p, 4); p += __shfl_xor(p, 2); p += __shfl_xor(p, 1);
        const float sc = expf(fminf(fmaxf(p * 0.17677669529663687f, -10.f), 10.f));
        #pragma unroll
        for (int u = 0; u < 4; u++) acc[u] += (b2f(uv.h[u]) + e[u]) * sc;
        z += sc;
    }
    U4 o;
    const float iz = 1.f / z;
    #pragma unroll
    for (int u = 0; u < 4; u++) o.h[u] = f2b(acc[u] * iz);
    *reinterpret_cast<int2*>(&O[(size_t)d * 256 + c4]) = o.v;
}

// ---------------------------------------------------------------------------
// Edge attention (vectorized, verified r14): wave per dst, lane owns 4 cols.
// ---------------------------------------------------------------------------
__global__ __launch_bounds__(256) void attn_edge_f(
    const bf16* __restrict__ QE, const bf16* __restrict__ KVE,
    const int* __restrict__ lgsrc, bf16* __restrict__ O, int r0, int rows)
{
    const int w = threadIdx.x >> 6, lane = threadIdx.x & 63;
    const int b = blockIdx.x * 4 + w;
    if (b >= rows) return;
    const int dst = r0 + b;
    const int c4 = lane * 4;
    U4 uq; uq.v = *reinterpret_cast<const int2*>(&QE[(size_t)dst * 256 + c4]);
    float q[4];
    #pragma unroll
    for (int u = 0; u < 4; u++) q[u] = b2f(uq.h[u]);
    float acc[4] = {0.f, 0.f, 0.f, 0.f};
    float z = 0.f;
    #pragma unroll
    for (int j = 0; j < 2; j++) {
        const int s = lgsrc[dst + j * E_EDGES];
        const size_t kr = (size_t)s * 512;
        U4 uk; uk.v = *reinterpret_cast<const int2*>(&KVE[kr + c4]);
        U4 uv; uv.v = *reinterpret_cast<const int2*>(&KVE[kr + 256 + c4]);
        float p = 0.f;
        #pragma unroll
        for (int u = 0; u < 4; u++) p += b2f(uk.h[u]) * q[u];
        p += __shfl_xor(p, 4); p += __shfl_xor(p, 2); p += __shfl_xor(p, 1);
        const float sc = expf(fminf(fmaxf(p * 0.17677669529663687f, -10.f), 10.f));
        #pragma unroll
        for (int u = 0; u < 4; u++) acc[u] += b2f(uv.h[u]) * sc;
        z += sc;
    }
    U4 o;
    const float iz = 1.f / z;
    #pragma unroll
    for (int u = 0; u < 4; u++) o.h[u] = f2b(acc[u] * iz);
    *reinterpret_cast<int2*>(&O[(size_t)b * 256 + c4]) = o.v;
}

// ---------------------------------------------------------------------------
extern "C" void kernel_launch(void* const* d_in, const int* in_sizes, int n_in,
                              void* d_out, int out_size, void* d_ws, size_t ws_size,
                              hipStream_t stream)
{
    const void* x   = d_in[0];
    const void* lgx = d_in[1];
    const int* local_src = (const int*)d_in[3];
    const int* lg_src    = (const int*)d_in[5];
    const int* src_ids   = (const int*)d_in[7];
    const int* dst_ids   = (const int*)d_in[8];

    const void *nWq = d_in[9],  *nbq = d_in[10], *nWk = d_in[11], *nWv = d_in[12],
               *nWo = d_in[13], *nbo = d_in[14], *nln1g = d_in[15], *nln1b = d_in[16],
               *nW1 = d_in[17], *nb1 = d_in[18], *nW2 = d_in[19], *nb2 = d_in[20],
               *nln2g = d_in[21], *nln2b = d_in[22];
    const void *eWq = d_in[23], *ebq = d_in[24], *eWk = d_in[25], *eWv = d_in[26],
               *eWo = d_in[27], *ebo = d_in[28], *eln1g = d_in[29], *eln1b = d_in[30],
               *eW1 = d_in[31], *eb1 = d_in[32], *eW2 = d_in[33], *eb2 = d_in[34],
               *eln2g = d_in[35], *eln2b = d_in[36];

    const dim3 blk(256);
    const dim3 blk2(512);

    // ws: dflag 256B | Wt packs 3MB | x16 5.12MB | lgx16 81.92MB | KVE | QE |
    //     chunk arena.  ws measured ~696MB (r4/r5/r7 WRITE_SIZE signatures).
    int* dflag = (int*)d_ws;
    detect_dtype<<<1, 64, 0, stream>>>((const unsigned short*)x, dflag);

    bf16* pk = (bf16*)((char*)d_ws + 256);
    bf16 *pnWq = pk,            *pnWk = pk + 65536,   *pnWv = pk + 131072,
         *pnWo = pk + 196608,   *pnW1 = pk + 262144,  *pnW2 = pk + 524288,
         *peWq = pk + 786432,   *peWk = pk + 851968,  *peWv = pk + 917504,
         *peWo = pk + 983040,   *peW1 = pk + 1048576, *peW2 = pk + 1310720;
    bf16* x16   = pk + 1572864;
    bf16* lgx16 = x16 + (size_t)N_NODES * 256;

    cvt_bf16<<<1250,  blk, 0, stream>>>(x,   x16,   (long)N_NODES * 32, dflag);
    cvt_bf16<<<20000, blk, 0, stream>>>(lgx, lgx16, (long)E_EDGES * 32, dflag);

    pack_wT<<<256,  blk, 0, stream>>>(nWq, pnWq, 256, 256,  dflag);
    pack_wT<<<256,  blk, 0, stream>>>(nWk, pnWk, 256, 256,  dflag);
    pack_wT<<<256,  blk, 0, stream>>>(nWv, pnWv, 256, 256,  dflag);
    pack_wT<<<256,  blk, 0, stream>>>(nWo, pnWo, 256, 256,  dflag);
    pack_wT<<<1024, blk, 0, stream>>>(nW1, pnW1, 256, 1024, dflag);
    pack_wT<<<1024, blk, 0, stream>>>(nW2, pnW2, 1024, 256, dflag);
    pack_wT<<<256,  blk, 0, stream>>>(eWq, peWq, 256, 256,  dflag);
    pack_wT<<<256,  blk, 0, stream>>>(eWk, peWk, 256, 256,  dflag);
    pack_wT<<<256,  blk, 0, stream>>>(eWv, peWv, 256, 256,  dflag);
    pack_wT<<<256,  blk, 0, stream>>>(eWo, peWo, 256, 256,  dflag);
    pack_wT<<<1024, blk, 0, stream>>>(eW1, peW1, 256, 1024, dflag);
    pack_wT<<<1024, blk, 0, stream>>>(eW2, peW2, 1024, 256, dflag);

    // ===== node path: temps in d_out's dead out_lgx region (verified r3-r14)
    bf16* QKVN = (bf16*)((char*)d_out + (size_t)N_NODES * 256 * 4);
    bf16* ON   = QKVN + (size_t)N_NODES * 768;
    bf16* HN   = ON   + (size_t)N_NODES * 256;

    const int gx = (N_NODES + 127) / 128;     // 79
    const int gx64 = (N_NODES + 63) / 64;     // 157
    mg<0><<<dim3(6, gx), blk, 0, stream>>>(x16, N_NODES, 256, 768,
        pnWq, pnWk, pnWv, nbq, nullptr, nullptr, nullptr,
        QKVN, nullptr, dflag);
    attn_node<<<(N_NODES + 3) / 4, blk, 0, stream>>>(QKVN, local_src, lgx16, ON);
    mgln8<<<dim3(1, gx), blk2, 0, stream>>>(ON, N_NODES, 256,
        pnWo, nbo, x16, nln1g, nln1b, HN, dflag);
    mgffn<<<dim3(1, gx64), blk, 0, stream>>>(HN, N_NODES,
        pnW1, pnW2, nb1, nb2, nln2g, nln2b, d_out, 0, dflag);

    // ===== edge path =====
    const size_t hdr = 256 + 3145728 + (size_t)5120000 + (size_t)81920000;  // 90.19MB
    bf16* KVE = (bf16*)((char*)d_ws + hdr);                    // E x 512
    bf16* QE  = KVE + (size_t)E_EDGES * 512;                   // E x 256
    char* arena = (char*)(QE + (size_t)E_EDGES * 256);

    const size_t used = hdr + (size_t)E_EDGES * 768 * 2;       // 335.95MB
    long CH = (long)(((ws_size > used ? ws_size - used : 0) / 1024) / 128 * 128);
    if (CH > E_EDGES) CH = E_EDGES;
    if (CH < 128) CH = 128;

    bf16* OE = (bf16*)arena;                                   // CH x 256
    bf16* HE = OE + (size_t)CH * 256;                          // CH x 256

    const int ge = (E_EDGES + 127) / 128;  // 1250
    mg<7><<<dim3(6, ge), blk, 0, stream>>>(lgx16, E_EDGES, 256, 768,
        peWq, peWk, peWv, ebq, x16, src_ids, dst_ids,
        QE, KVE, dflag);

    for (long r0 = 0; r0 < E_EDGES; r0 += CH) {
        const int rows = (int)(((E_EDGES - r0) < CH) ? (E_EDGES - r0) : CH);
        const int gm = (rows + 127) / 128;
        const int gm64 = (rows + 63) / 64;

        attn_edge_f<<<(rows + 3) / 4, blk, 0, stream>>>(QE, KVE, lg_src, OE, (int)r0, rows);
        mgln8<<<dim3(1, gm), blk2, 0, stream>>>(OE, rows, 256,
            peWo, ebo, lgx16 + (size_t)r0 * 256, eln1g, eln1b, HE, dflag);
        mgffn<<<dim3(1, gm64), blk, 0, stream>>>(HE, rows,
            peW1, peW2, eb1, eb2, eln2g, eln2b, d_out,
            (long)N_NODES * 256 + r0 * 256, dflag);
    }
}

// Round 16
// 1034.669 us; speedup vs baseline: 1.1748x; 1.1748x over previous
//
#include <hip/hip_runtime.h>
#include <hip/hip_bf16.h>

typedef __hip_bfloat16 bf16;
typedef __attribute__((ext_vector_type(8))) short short8v;
typedef __attribute__((ext_vector_type(4))) float float4v;

#define N_NODES 10000
#define E_EDGES 160000

__device__ __forceinline__ float b2f(bf16 v){ return __bfloat162float(v); }
__device__ __forceinline__ bf16 f2b(float v){ return __float2bfloat16(v); }

union U8 { int4 v; bf16 h[8]; };
union U4 { int2 v; bf16 h[4]; };

// ---- dtype-flexible external accessors (flag: 1 = bf16, 0 = f32) ----------
__device__ __forceinline__ float ldx(const void* p, size_t i, bool isb){
    return isb ? b2f(((const bf16*)p)[i]) : ((const float*)p)[i];
}
__device__ __forceinline__ void ld8(const void* p, size_t i, bool isb, float* o){
    if (isb) {
        U8 u; u.v = *reinterpret_cast<const int4*>((const bf16*)p + i);
        #pragma unroll
        for (int j = 0; j < 8; j++) o[j] = b2f(u.h[j]);
    } else {
        const float4* q = reinterpret_cast<const float4*>((const float*)p + i);
        float4 a = q[0], b = q[1];
        o[0]=a.x; o[1]=a.y; o[2]=a.z; o[3]=a.w; o[4]=b.x; o[5]=b.y; o[6]=b.z; o[7]=b.w;
    }
}
__device__ __forceinline__ void stx(void* p, size_t i, bool isb, float v){
    if (isb) ((bf16*)p)[i] = f2b(v); else ((float*)p)[i] = v;
}

// async global->LDS, 16 B/lane (HW: LDS dest = wave-uniform base + lane*16)
typedef const __attribute__((address_space(1))) void* gas_p;
typedef __attribute__((address_space(3))) void* las_p;
__device__ __forceinline__ void gl16(const bf16* g, bf16* l){
    __builtin_amdgcn_global_load_lds((gas_p)g, (las_p)l, 16, 0, 0);
}

// 4x4 in-register transpose across 4 lanes (verified r9-r14):
// input: a[r] = M[r][t] (t = lane&3); output: a[u] = M[t][u]
__device__ __forceinline__ void quadT(float* a, int t){
    float x0 = (t & 1) ? a[0] : a[1];
    float y0 = __shfl_xor(x0, 1);
    if (t & 1) a[0] = y0; else a[1] = y0;
    float x1 = (t & 1) ? a[2] : a[3];
    float y1 = __shfl_xor(x1, 1);
    if (t & 1) a[2] = y1; else a[3] = y1;
    float x2 = (t & 2) ? a[0] : a[2];
    float y2 = __shfl_xor(x2, 2);
    if (t & 2) a[0] = y2; else a[2] = y2;
    float x3 = (t & 2) ? a[1] : a[3];
    float y3 = __shfl_xor(x3, 2);
    if (t & 2) a[1] = y3; else a[3] = y3;
}

// XCD-bijective swizzle of a linear workgroup id
__device__ __forceinline__ int xcd_swz(int wg, int nwg){
    const int q = nwg >> 3, r = nwg & 7;
    const int xcd = wg & 7, ix = wg >> 3;
    return (xcd < r ? xcd * (q + 1) : r * (q + 1) + (xcd - r) * q) + ix;
}

// ---------------------------------------------------------------------------
__global__ void detect_dtype(const unsigned short* __restrict__ xw, int* __restrict__ flag){
    const int lane = threadIdx.x;  // 64 threads
    int cnt = 0;
    for (int i = lane; i < 8192; i += 64) {
        const unsigned e = (xw[i] >> 7) & 0xFF;
        if (e == 0 || (e >= 100 && e <= 140)) cnt++;
    }
    #pragma unroll
    for (int off = 32; off >= 1; off >>= 1) cnt += __shfl_xor(cnt, off);
    if (lane == 0) *flag = (cnt >= 6554) ? 1 : 0;
}

__global__ __launch_bounds__(256) void cvt_bf16(
    const void* __restrict__ in, bf16* __restrict__ out, long n8, const int* __restrict__ dflag)
{
    const bool isb = (*dflag != 0);
    const long t = (long)blockIdx.x * 256 + threadIdx.x;
    if (t >= n8) return;
    float f[8]; ld8(in, (size_t)t * 8, isb, f);
    U8 u;
    #pragma unroll
    for (int j = 0; j < 8; j++) u.h[j] = f2b(f[j]);
    *reinterpret_cast<int4*>(&out[t * 8]) = u.v;
}

// pack W[K,Nmat] -> Wt[Nmat][K] bf16
__global__ __launch_bounds__(256) void pack_wT(
    const void* __restrict__ W, bf16* __restrict__ out,
    int K, int Nmat, const int* __restrict__ dflag)
{
    const bool isb = (*dflag != 0);
    const int idx = blockIdx.x * 256 + threadIdx.x;
    if (idx >= K * Nmat) return;
    const int k = idx / Nmat, n = idx - k * Nmat;
    out[(size_t)n * K + k] = f2b(ldx(W, idx, isb));
}

// ---------------------------------------------------------------------------
// MFMA GEMM v7 (verified r10-r14): BK=64 single-buffer + quadT epilogue.
// BM=BN=128, 4 waves 2x2.
// MODE 0: node QKV (Bt0|1|2 segmented NC=768; bias on col<256)
// MODE 3: FFN1 relu(+bias), NC=1024
// MODE 7: edge QKV fused (seg0 -> C=QE +bias+xg[sidx]; seg1 -> C2=KVE.k;
//         seg2 -> C2=KVE.v +xg[didx])
// ---------------------------------------------------------------------------
template<int MODE>
__global__ __launch_bounds__(256) void mg(
    const bf16* __restrict__ A, int M, int K, int NC,
    const bf16* __restrict__ Bt0, const bf16* __restrict__ Bt1, const bf16* __restrict__ Bt2,
    const void* __restrict__ bias,
    const bf16* __restrict__ xg,
    const int* __restrict__ sidx, const int* __restrict__ didx,
    bf16* __restrict__ C, bf16* __restrict__ C2,
    const int* __restrict__ dflag)
{
    const bool isb = (*dflag != 0);
    __shared__ __align__(16) bf16 Al[128 * 64];
    __shared__ __align__(16) bf16 Bl[128 * 64];
    __shared__ float biasl[128];

    const int tid = threadIdx.x;
    const int lane = tid & 63, wave = tid >> 6;
    const int l15 = lane & 15, g = lane >> 4;
    const int t4 = l15 & 3, qd = l15 >> 2;
    const int wr = wave >> 1, wc = wave & 1;

    const int nwgx = gridDim.x;
    int wg = xcd_swz(blockIdx.y * nwgx + blockIdx.x, nwgx * gridDim.y);
    const int rb = (wg / nwgx) * 128, cb = (wg % nwgx) * 128;

    const bf16* Bsel; int cloc;
    if (MODE == 0 || MODE == 7) {
        const int seg = cb >> 8;
        Bsel = (seg == 0) ? Bt0 : ((seg == 1) ? Bt1 : Bt2);
        cloc = cb & 255;
    } else { Bsel = Bt0; cloc = cb; }

    if (tid < 128) {
        float bv = 0.f;
        const int gc = cb + tid;
        if (MODE == 0 || MODE == 7) { if (gc < 256) bv = ldx(bias, gc, isb); }
        else bv = ldx(bias, gc, isb);
        biasl[tid] = bv;
    }

    const int sp = lane & 7, sr8 = lane >> 3;
    int rls[4]; long arows[4];
    #pragma unroll
    for (int j = 0; j < 4; j++) {
        const int rl = wave * 32 + j * 8 + sr8;
        rls[j] = rl;
        const int gm = rb + rl;
        arows[j] = (gm < M) ? gm : (M - 1);
    }

    float4v acc[4][4];
    #pragma unroll
    for (int i = 0; i < 4; i++)
        #pragma unroll
        for (int j = 0; j < 4; j++)
            acc[i][j] = (float4v){0.f, 0.f, 0.f, 0.f};

    for (int k0 = 0; k0 < K; k0 += 64) {
        #pragma unroll
        for (int j = 0; j < 4; j++) {
            const int rl = rls[j];
            const int pp = sp ^ (rl & 7);
            gl16(A + arows[j] * K + k0 + pp * 8,                 Al + rl * 64 + sp * 8);
            gl16(Bsel + (size_t)(cloc + rl) * K + k0 + pp * 8,   Bl + rl * 64 + sp * 8);
        }
        __syncthreads();
        #pragma unroll
        for (int ks = 0; ks < 2; ks++) {
            short8v av[4], bv[4];
            #pragma unroll
            for (int mi = 0; mi < 4; mi++) {
                const int row = wr * 64 + mi * 16 + l15;
                const int cp = (ks * 4 + g) ^ (row & 7);
                av[mi] = *reinterpret_cast<const short8v*>(&Al[row * 64 + cp * 8]);
            }
            #pragma unroll
            for (int ni = 0; ni < 4; ni++) {
                const int row = wc * 64 + ni * 16 + l15;
                const int cp = (ks * 4 + g) ^ (row & 7);
                bv[ni] = *reinterpret_cast<const short8v*>(&Bl[row * 64 + cp * 8]);
            }
            #pragma unroll
            for (int mi = 0; mi < 4; mi++)
                #pragma unroll
                for (int ni = 0; ni < 4; ni++)
                    acc[mi][ni] = __builtin_amdgcn_mfma_f32_16x16x32_bf16(
                        av[mi], bv[ni], acc[mi][ni], 0, 0, 0);
        }
        __syncthreads();
    }

    #pragma unroll
    for (int mi = 0; mi < 4; mi++) {
        const int grow = rb + wr * 64 + mi * 16 + g * 4 + t4;
        const bool ok = (grow < M);
        int s5 = 0, d5 = 0;
        if (MODE == 7 && ok) {
            if (cb < 256) s5 = sidx[grow];
            else if (cb >= 512) d5 = didx[grow];
        }
        #pragma unroll
        for (int ni = 0; ni < 4; ni++) {
            float a[4];
            #pragma unroll
            for (int r = 0; r < 4; r++) a[r] = acc[mi][ni][r];
            quadT(a, t4);
            if (!ok) continue;
            const int ct = wc * 64 + ni * 16 + qd * 4;
            const int gc = cb + ct;
            if (MODE == 0) {
                if (gc < 256) {
                    #pragma unroll
                    for (int u = 0; u < 4; u++) a[u] += biasl[ct + u];
                }
            }
            if (MODE == 3) {
                #pragma unroll
                for (int u = 0; u < 4; u++) a[u] = fmaxf(a[u] + biasl[ct + u], 0.f);
            }
            if (MODE == 7) {
                if (gc < 256) {
                    U4 xx; xx.v = *reinterpret_cast<const int2*>(&xg[(size_t)s5 * 256 + gc]);
                    #pragma unroll
                    for (int u = 0; u < 4; u++) a[u] += biasl[ct + u] + b2f(xx.h[u]);
                } else if (gc >= 512) {
                    U4 xx; xx.v = *reinterpret_cast<const int2*>(&xg[(size_t)d5 * 256 + (gc - 512)]);
                    #pragma unroll
                    for (int u = 0; u < 4; u++) a[u] += b2f(xx.h[u]);
                }
            }
            U4 o;
            #pragma unroll
            for (int u = 0; u < 4; u++) o.h[u] = f2b(a[u]);
            if (MODE == 7) {
                if (gc < 256) *reinterpret_cast<int2*>(&C[(size_t)grow * 256 + gc]) = o.v;
                else          *reinterpret_cast<int2*>(&C2[(size_t)grow * 512 + (gc - 256)]) = o.v;
            } else {
                *reinterpret_cast<int2*>(&C[(size_t)grow * NC + gc]) = o.v;
            }
        }
    }
}

// ---------------------------------------------------------------------------
// LN-fused GEMM (verified r11-r14): 512 thr, 8 waves (2x4), BM=128, BN=256.
// MODE 8: C bf16.  MODE 9: outv dtype-flex at element obase.
// ---------------------------------------------------------------------------
template<int MODE>
__global__ __launch_bounds__(512) void mgln(
    const bf16* __restrict__ A, int M, int K,
    const bf16* __restrict__ Bt,
    const void* __restrict__ bias,
    const bf16* __restrict__ resid,
    const void* __restrict__ lng, const void* __restrict__ lnb,
    bf16* __restrict__ C, void* __restrict__ outv, long obase,
    const int* __restrict__ dflag)
{
    const bool isb = (*dflag != 0);
    __shared__ __align__(16) bf16 Al[128 * 64];   // 16KB (Ps overlay)
    __shared__ __align__(16) bf16 Bl[256 * 64];   // 32KB (Mr/Rsd overlay)
    __shared__ float biasl[256];
    __shared__ float lngl[256];
    __shared__ float lnbl[256];

    const int tid = threadIdx.x;
    const int lane = tid & 63, wave = tid >> 6;
    const int l15 = lane & 15, g = lane >> 4;
    const int t4 = l15 & 3, qd = l15 >> 2;
    const int wr = wave >> 2, wc = wave & 3;   // 2 x 4 wave grid

    const int wg = xcd_swz(blockIdx.y, gridDim.y);
    const int rb = wg * 128;

    if (tid < 256) {
        biasl[tid] = ldx(bias, tid, isb);
        lngl[tid]  = ldx(lng,  tid, isb);
        lnbl[tid]  = ldx(lnb,  tid, isb);
    }

    const int sp = lane & 7, sr8 = lane >> 3;
    int rlA[2]; long arA[2];
    #pragma unroll
    for (int j = 0; j < 2; j++) {
        const int rl = wave * 16 + j * 8 + sr8;
        rlA[j] = rl;
        const int gm = rb + rl;
        arA[j] = (gm < M) ? gm : (M - 1);
    }
    int rlB[4];
    #pragma unroll
    for (int j = 0; j < 4; j++) rlB[j] = wave * 32 + j * 8 + sr8;

    float4v acc[4][4];
    #pragma unroll
    for (int i = 0; i < 4; i++)
        #pragma unroll
        for (int j = 0; j < 4; j++)
            acc[i][j] = (float4v){0.f, 0.f, 0.f, 0.f};

    for (int k0 = 0; k0 < K; k0 += 64) {
        #pragma unroll
        for (int j = 0; j < 2; j++) {
            const int pp = sp ^ (rlA[j] & 7);
            gl16(A + arA[j] * K + k0 + pp * 8, Al + rlA[j] * 64 + sp * 8);
        }
        #pragma unroll
        for (int j = 0; j < 4; j++) {
            const int pp = sp ^ (rlB[j] & 7);
            gl16(Bt + (size_t)rlB[j] * K + k0 + pp * 8, Bl + rlB[j] * 64 + sp * 8);
        }
        __syncthreads();
        #pragma unroll
        for (int ks = 0; ks < 2; ks++) {
            short8v av[4], bv[4];
            #pragma unroll
            for (int mi = 0; mi < 4; mi++) {
                const int row = wr * 64 + mi * 16 + l15;
                const int cp = (ks * 4 + g) ^ (row & 7);
                av[mi] = *reinterpret_cast<const short8v*>(&Al[row * 64 + cp * 8]);
            }
            #pragma unroll
            for (int ni = 0; ni < 4; ni++) {
                const int row = wc * 64 + ni * 16 + l15;
                const int cp = (ks * 4 + g) ^ (row & 7);
                bv[ni] = *reinterpret_cast<const short8v*>(&Bl[row * 64 + cp * 8]);
            }
            #pragma unroll
            for (int mi = 0; mi < 4; mi++)
                #pragma unroll
                for (int ni = 0; ni < 4; ni++)
                    acc[mi][ni] = __builtin_amdgcn_mfma_f32_16x16x32_bf16(
                        av[mi], bv[ni], acc[mi][ni], 0, 0, 0);
        }
        __syncthreads();
    }

    float s1[4] = {0.f,0.f,0.f,0.f}, s2[4] = {0.f,0.f,0.f,0.f};
    #pragma unroll
    for (int mi = 0; mi < 4; mi++) {
        const int grow = rb + wr * 64 + mi * 16 + g * 4 + t4;
        const bool ok = (grow < M);
        #pragma unroll
        for (int ni = 0; ni < 4; ni++) {
            float a[4];
            #pragma unroll
            for (int r = 0; r < 4; r++) a[r] = acc[mi][ni][r];
            quadT(a, t4);
            const int ct = wc * 64 + ni * 16 + qd * 4;
            U4 rr; rr.v = make_int2(0, 0);
            if (ok) rr.v = *reinterpret_cast<const int2*>(&resid[(size_t)grow * 256 + ct]);
            #pragma unroll
            for (int u = 0; u < 4; u++) {
                a[u] += biasl[ct + u] + b2f(rr.h[u]);
                s1[mi] += a[u];
                s2[mi] += a[u] * a[u];
                acc[mi][ni][u] = a[u];
            }
        }
    }
    float* Ps1 = (float*)Al;          // [16][128]
    float* Ps2 = Ps1 + 2048;
    #pragma unroll
    for (int mi = 0; mi < 4; mi++) {
        const int rowl = wr * 64 + mi * 16 + g * 4 + t4;
        Ps1[(wc * 4 + qd) * 128 + rowl] = s1[mi];
        Ps2[(wc * 4 + qd) * 128 + rowl] = s2[mi];
    }
    __syncthreads();
    float* Mr  = (float*)Bl;
    float* Rsd = Mr + 128;
    if (tid < 128) {
        float a1 = 0.f, a2 = 0.f;
        #pragma unroll
        for (int k = 0; k < 16; k++) { a1 += Ps1[k * 128 + tid]; a2 += Ps2[k * 128 + tid]; }
        const float mn = a1 * (1.f / 256.f);
        const float var = a2 * (1.f / 256.f) - mn * mn;
        Mr[tid] = mn;
        Rsd[tid] = rsqrtf(fmaxf(var, 0.f) + 1e-5f);
    }
    __syncthreads();
    #pragma unroll
    for (int mi = 0; mi < 4; mi++) {
        const int rowl = wr * 64 + mi * 16 + g * 4 + t4;
        const int grow = rb + rowl;
        if (grow >= M) continue;
        const float mn = Mr[rowl], rd = Rsd[rowl];
        #pragma unroll
        for (int ni = 0; ni < 4; ni++) {
            const int ct = wc * 64 + ni * 16 + qd * 4;
            float o[4];
            #pragma unroll
            for (int u = 0; u < 4; u++)
                o[u] = (acc[mi][ni][u] - mn) * rd * lngl[ct + u] + lnbl[ct + u];
            if (MODE == 8) {
                U4 ob;
                #pragma unroll
                for (int u = 0; u < 4; u++) ob.h[u] = f2b(o[u]);
                *reinterpret_cast<int2*>(&C[(size_t)grow * 256 + ct]) = ob.v;
            } else {
                if (isb) {
                    U4 ob;
                    #pragma unroll
                    for (int u = 0; u < 4; u++) ob.h[u] = f2b(o[u]);
                    *reinterpret_cast<int2*>((bf16*)outv + obase + (size_t)grow * 256 + ct) = ob.v;
                } else {
                    float4 f4 = make_float4(o[0], o[1], o[2], o[3]);
                    *reinterpret_cast<float4*>((float*)outv + obase + (size_t)grow * 256 + ct) = f4;
                }
            }
        }
    }
}

// ---------------------------------------------------------------------------
// Node attention (vectorized, verified r14): wave per node, lane owns 4 cols.
// ---------------------------------------------------------------------------
__global__ __launch_bounds__(256) void attn_node(
    const bf16* __restrict__ QKV, const int* __restrict__ lsrc,
    const bf16* __restrict__ lgx16, bf16* __restrict__ O)
{
    const int w = threadIdx.x >> 6, lane = threadIdx.x & 63;
    const int d = blockIdx.x * 4 + w;
    if (d >= N_NODES) return;
    const int c4 = lane * 4;
    U4 uq; uq.v = *reinterpret_cast<const int2*>(&QKV[(size_t)d * 768 + c4]);
    float q[4];
    #pragma unroll
    for (int u = 0; u < 4; u++) q[u] = b2f(uq.h[u]);
    float acc[4] = {0.f, 0.f, 0.f, 0.f};
    float z = 0.f;
    for (int j = 0; j < 16; j++) {
        const int i = d + j * N_NODES;
        const int s = lsrc[i];
        U4 ue; ue.v = *reinterpret_cast<const int2*>(&lgx16[(size_t)i * 256 + c4]);
        U4 uk; uk.v = *reinterpret_cast<const int2*>(&QKV[(size_t)s * 768 + 256 + c4]);
        U4 uv; uv.v = *reinterpret_cast<const int2*>(&QKV[(size_t)s * 768 + 512 + c4]);
        float e[4], p = 0.f;
        #pragma unroll
        for (int u = 0; u < 4; u++) {
            e[u] = b2f(ue.h[u]);
            p += (b2f(uk.h[u]) + e[u]) * q[u];
        }
        p += __shfl_xor(p, 4); p += __shfl_xor(p, 2); p += __shfl_xor(p, 1);
        const float sc = expf(fminf(fmaxf(p * 0.17677669529663687f, -10.f), 10.f));
        #pragma unroll
        for (int u = 0; u < 4; u++) acc[u] += (b2f(uv.h[u]) + e[u]) * sc;
        z += sc;
    }
    U4 o;
    const float iz = 1.f / z;
    #pragma unroll
    for (int u = 0; u < 4; u++) o.h[u] = f2b(acc[u] * iz);
    *reinterpret_cast<int2*>(&O[(size_t)d * 256 + c4]) = o.v;
}

// ---------------------------------------------------------------------------
// Edge attention (vectorized, verified r14): wave per dst, lane owns 4 cols.
// ---------------------------------------------------------------------------
__global__ __launch_bounds__(256) void attn_edge_f(
    const bf16* __restrict__ QE, const bf16* __restrict__ KVE,
    const int* __restrict__ lgsrc, bf16* __restrict__ O, int r0, int rows)
{
    const int w = threadIdx.x >> 6, lane = threadIdx.x & 63;
    const int b = blockIdx.x * 4 + w;
    if (b >= rows) return;
    const int dst = r0 + b;
    const int c4 = lane * 4;
    U4 uq; uq.v = *reinterpret_cast<const int2*>(&QE[(size_t)dst * 256 + c4]);
    float q[4];
    #pragma unroll
    for (int u = 0; u < 4; u++) q[u] = b2f(uq.h[u]);
    float acc[4] = {0.f, 0.f, 0.f, 0.f};
    float z = 0.f;
    #pragma unroll
    for (int j = 0; j < 2; j++) {
        const int s = lgsrc[dst + j * E_EDGES];
        const size_t kr = (size_t)s * 512;
        U4 uk; uk.v = *reinterpret_cast<const int2*>(&KVE[kr + c4]);
        U4 uv; uv.v = *reinterpret_cast<const int2*>(&KVE[kr + 256 + c4]);
        float p = 0.f;
        #pragma unroll
        for (int u = 0; u < 4; u++) p += b2f(uk.h[u]) * q[u];
        p += __shfl_xor(p, 4); p += __shfl_xor(p, 2); p += __shfl_xor(p, 1);
        const float sc = expf(fminf(fmaxf(p * 0.17677669529663687f, -10.f), 10.f));
        #pragma unroll
        for (int u = 0; u < 4; u++) acc[u] += b2f(uv.h[u]) * sc;
        z += sc;
    }
    U4 o;
    const float iz = 1.f / z;
    #pragma unroll
    for (int u = 0; u < 4; u++) o.h[u] = f2b(acc[u] * iz);
    *reinterpret_cast<int2*>(&O[(size_t)b * 256 + c4]) = o.v;
}

// ---------------------------------------------------------------------------
extern "C" void kernel_launch(void* const* d_in, const int* in_sizes, int n_in,
                              void* d_out, int out_size, void* d_ws, size_t ws_size,
                              hipStream_t stream)
{
    const void* x   = d_in[0];
    const void* lgx = d_in[1];
    const int* local_src = (const int*)d_in[3];
    const int* lg_src    = (const int*)d_in[5];
    const int* src_ids   = (const int*)d_in[7];
    const int* dst_ids   = (const int*)d_in[8];

    const void *nWq = d_in[9],  *nbq = d_in[10], *nWk = d_in[11], *nWv = d_in[12],
               *nWo = d_in[13], *nbo = d_in[14], *nln1g = d_in[15], *nln1b = d_in[16],
               *nW1 = d_in[17], *nb1 = d_in[18], *nW2 = d_in[19], *nb2 = d_in[20],
               *nln2g = d_in[21], *nln2b = d_in[22];
    const void *eWq = d_in[23], *ebq = d_in[24], *eWk = d_in[25], *eWv = d_in[26],
               *eWo = d_in[27], *ebo = d_in[28], *eln1g = d_in[29], *eln1b = d_in[30],
               *eW1 = d_in[31], *eb1 = d_in[32], *eW2 = d_in[33], *eb2 = d_in[34],
               *eln2g = d_in[35], *eln2b = d_in[36];

    const dim3 blk(256);
    const dim3 blk2(512);

    // ws: dflag 256B | Wt packs 3MB | x16 5.12MB | lgx16 81.92MB | KVE | QE |
    //     chunk arena.  ws measured ~696MB (r4/r5/r7 WRITE_SIZE signatures).
    int* dflag = (int*)d_ws;
    detect_dtype<<<1, 64, 0, stream>>>((const unsigned short*)x, dflag);

    bf16* pk = (bf16*)((char*)d_ws + 256);
    bf16 *pnWq = pk,            *pnWk = pk + 65536,   *pnWv = pk + 131072,
         *pnWo = pk + 196608,   *pnW1 = pk + 262144,  *pnW2 = pk + 524288,
         *peWq = pk + 786432,   *peWk = pk + 851968,  *peWv = pk + 917504,
         *peWo = pk + 983040,   *peW1 = pk + 1048576, *peW2 = pk + 1310720;
    bf16* x16   = pk + 1572864;
    bf16* lgx16 = x16 + (size_t)N_NODES * 256;

    cvt_bf16<<<1250,  blk, 0, stream>>>(x,   x16,   (long)N_NODES * 32, dflag);
    cvt_bf16<<<20000, blk, 0, stream>>>(lgx, lgx16, (long)E_EDGES * 32, dflag);

    pack_wT<<<256,  blk, 0, stream>>>(nWq, pnWq, 256, 256,  dflag);
    pack_wT<<<256,  blk, 0, stream>>>(nWk, pnWk, 256, 256,  dflag);
    pack_wT<<<256,  blk, 0, stream>>>(nWv, pnWv, 256, 256,  dflag);
    pack_wT<<<256,  blk, 0, stream>>>(nWo, pnWo, 256, 256,  dflag);
    pack_wT<<<1024, blk, 0, stream>>>(nW1, pnW1, 256, 1024, dflag);
    pack_wT<<<1024, blk, 0, stream>>>(nW2, pnW2, 1024, 256, dflag);
    pack_wT<<<256,  blk, 0, stream>>>(eWq, peWq, 256, 256,  dflag);
    pack_wT<<<256,  blk, 0, stream>>>(eWk, peWk, 256, 256,  dflag);
    pack_wT<<<256,  blk, 0, stream>>>(eWv, peWv, 256, 256,  dflag);
    pack_wT<<<256,  blk, 0, stream>>>(eWo, peWo, 256, 256,  dflag);
    pack_wT<<<1024, blk, 0, stream>>>(eW1, peW1, 256, 1024, dflag);
    pack_wT<<<1024, blk, 0, stream>>>(eW2, peW2, 1024, 256, dflag);

    // ===== node path: temps in d_out's dead out_lgx region (verified r3-r14)
    bf16* QKVN = (bf16*)((char*)d_out + (size_t)N_NODES * 256 * 4);
    bf16* ON   = QKVN + (size_t)N_NODES * 768;
    bf16* HN   = ON   + (size_t)N_NODES * 256;
    bf16* FN   = HN   + (size_t)N_NODES * 256;

    const int gx = (N_NODES + 127) / 128;   // 79
    mg<0><<<dim3(6, gx), blk, 0, stream>>>(x16, N_NODES, 256, 768,
        pnWq, pnWk, pnWv, nbq, nullptr, nullptr, nullptr,
        QKVN, nullptr, dflag);
    attn_node<<<(N_NODES + 3) / 4, blk, 0, stream>>>(QKVN, local_src, lgx16, ON);
    mgln<8><<<dim3(1, gx), blk2, 0, stream>>>(ON, N_NODES, 256,
        pnWo, nbo, x16, nln1g, nln1b, HN, nullptr, 0, dflag);
    mg<3><<<dim3(8, gx), blk, 0, stream>>>(HN, N_NODES, 256, 1024,
        pnW1, nullptr, nullptr, nb1, nullptr, nullptr, nullptr,
        FN, nullptr, dflag);
    mgln<9><<<dim3(1, gx), blk2, 0, stream>>>(FN, N_NODES, 1024,
        pnW2, nb2, HN, nln2g, nln2b, nullptr, d_out, 0, dflag);

    // ===== edge path =====
    const size_t hdr = 256 + 3145728 + (size_t)5120000 + (size_t)81920000;  // 90.19MB
    bf16* KVE = (bf16*)((char*)d_ws + hdr);                    // E x 512
    bf16* QE  = KVE + (size_t)E_EDGES * 512;                   // E x 256
    char* arena = (char*)(QE + (size_t)E_EDGES * 256);

    const size_t used = hdr + (size_t)E_EDGES * 768 * 2;       // 335.95MB
    long CH = (long)(((ws_size > used ? ws_size - used : 0) / 3072) / 128 * 128);
    if (CH > E_EDGES) CH = E_EDGES;
    if (CH < 128) CH = 128;

    bf16* OE = (bf16*)arena;                                   // CH x 256
    bf16* HE = OE + (size_t)CH * 256;                          // CH x 256
    bf16* FE = HE + (size_t)CH * 256;                          // CH x 1024

    const int ge = (E_EDGES + 127) / 128;  // 1250
    mg<7><<<dim3(6, ge), blk, 0, stream>>>(lgx16, E_EDGES, 256, 768,
        peWq, peWk, peWv, ebq, x16, src_ids, dst_ids,
        QE, KVE, dflag);

    for (long r0 = 0; r0 < E_EDGES; r0 += CH) {
        const int rows = (int)(((E_EDGES - r0) < CH) ? (E_EDGES - r0) : CH);
        const int gm = (rows + 127) / 128;

        attn_edge_f<<<(rows + 3) / 4, blk, 0, stream>>>(QE, KVE, lg_src, OE, (int)r0, rows);
        mgln<8><<<dim3(1, gm), blk2, 0, stream>>>(OE, rows, 256,
            peWo, ebo, lgx16 + (size_t)r0 * 256, eln1g, eln1b, HE, nullptr, 0, dflag);
        mg<3><<<dim3(8, gm), blk, 0, stream>>>(HE, rows, 256, 1024,
            peW1, nullptr, nullptr, eb1, nullptr, nullptr, nullptr,
            FE, nullptr, dflag);
        mgln<9><<<dim3(1, gm), blk2, 0, stream>>>(FE, rows, 1024,
            peW2, eb2, HE, eln2g, eln2b, nullptr, d_out,
            (long)N_NODES * 256 + r0 * 256, dflag);
    }
}

// Round 17
// 987.482 us; speedup vs baseline: 1.2309x; 1.0478x over previous
//
#include <hip/hip_runtime.h>
#include <hip/hip_bf16.h>

typedef __hip_bfloat16 bf16;
typedef __attribute__((ext_vector_type(8))) short short8v;
typedef __attribute__((ext_vector_type(4))) float float4v;

#define N_NODES 10000
#define E_EDGES 160000

__device__ __forceinline__ float b2f(bf16 v){ return __bfloat162float(v); }
__device__ __forceinline__ bf16 f2b(float v){ return __float2bfloat16(v); }

union U8 { int4 v; bf16 h[8]; };
union U4 { int2 v; bf16 h[4]; };

// ---- dtype-flexible external accessors (flag: 1 = bf16, 0 = f32) ----------
__device__ __forceinline__ float ldx(const void* p, size_t i, bool isb){
    return isb ? b2f(((const bf16*)p)[i]) : ((const float*)p)[i];
}
__device__ __forceinline__ void ld8(const void* p, size_t i, bool isb, float* o){
    if (isb) {
        U8 u; u.v = *reinterpret_cast<const int4*>((const bf16*)p + i);
        #pragma unroll
        for (int j = 0; j < 8; j++) o[j] = b2f(u.h[j]);
    } else {
        const float4* q = reinterpret_cast<const float4*>((const float*)p + i);
        float4 a = q[0], b = q[1];
        o[0]=a.x; o[1]=a.y; o[2]=a.z; o[3]=a.w; o[4]=b.x; o[5]=b.y; o[6]=b.z; o[7]=b.w;
    }
}
__device__ __forceinline__ void stx(void* p, size_t i, bool isb, float v){
    if (isb) ((bf16*)p)[i] = f2b(v); else ((float*)p)[i] = v;
}

// async global->LDS, 16 B/lane (HW: LDS dest = wave-uniform base + lane*16)
typedef const __attribute__((address_space(1))) void* gas_p;
typedef __attribute__((address_space(3))) void* las_p;
__device__ __forceinline__ void gl16(const bf16* g, bf16* l){
    __builtin_amdgcn_global_load_lds((gas_p)g, (las_p)l, 16, 0, 0);
}

// 4x4 in-register transpose across 4 lanes (verified r9-r16)
__device__ __forceinline__ void quadT(float* a, int t){
    float x0 = (t & 1) ? a[0] : a[1];
    float y0 = __shfl_xor(x0, 1);
    if (t & 1) a[0] = y0; else a[1] = y0;
    float x1 = (t & 1) ? a[2] : a[3];
    float y1 = __shfl_xor(x1, 1);
    if (t & 1) a[2] = y1; else a[3] = y1;
    float x2 = (t & 2) ? a[0] : a[2];
    float y2 = __shfl_xor(x2, 2);
    if (t & 2) a[0] = y2; else a[2] = y2;
    float x3 = (t & 2) ? a[1] : a[3];
    float y3 = __shfl_xor(x3, 2);
    if (t & 2) a[1] = y3; else a[3] = y3;
}

// XCD-bijective swizzle of a linear workgroup id
__device__ __forceinline__ int xcd_swz(int wg, int nwg){
    const int q = nwg >> 3, r = nwg & 7;
    const int xcd = wg & 7, ix = wg >> 3;
    return (xcd < r ? xcd * (q + 1) : r * (q + 1) + (xcd - r) * q) + ix;
}

// ---------------------------------------------------------------------------
__global__ void detect_dtype(const unsigned short* __restrict__ xw, int* __restrict__ flag){
    const int lane = threadIdx.x;  // 64 threads
    int cnt = 0;
    for (int i = lane; i < 8192; i += 64) {
        const unsigned e = (xw[i] >> 7) & 0xFF;
        if (e == 0 || (e >= 100 && e <= 140)) cnt++;
    }
    #pragma unroll
    for (int off = 32; off >= 1; off >>= 1) cnt += __shfl_xor(cnt, off);
    if (lane == 0) *flag = (cnt >= 6554) ? 1 : 0;
}

__global__ __launch_bounds__(256) void cvt_bf16(
    const void* __restrict__ in, bf16* __restrict__ out, long n8, const int* __restrict__ dflag)
{
    const bool isb = (*dflag != 0);
    const long t = (long)blockIdx.x * 256 + threadIdx.x;
    if (t >= n8) return;
    float f[8]; ld8(in, (size_t)t * 8, isb, f);
    U8 u;
    #pragma unroll
    for (int j = 0; j < 8; j++) u.h[j] = f2b(f[j]);
    *reinterpret_cast<int4*>(&out[t * 8]) = u.v;
}

// ---------------------------------------------------------------------------
// pack_all: all 12 weight matrices -> transposed bf16 [Nmat][K] in one launch.
// Layout: m 0..7 = 256x256 (nWq,nWk,nWv,nWo,eWq,eWk,eWv,eWo);
//         m 8..11 = nW1(256x1024), nW2(1024x256), eW1, eW2.
// ---------------------------------------------------------------------------
struct PackArgs { const void* src[12]; bf16* dst[12]; };
__global__ __launch_bounds__(256) void pack_all(PackArgs pa, const int* __restrict__ dflag){
    const bool isb = (*dflag != 0);
    const long idx = (long)blockIdx.x * 256 + threadIdx.x;
    if (idx >= 1572864) return;
    int m, local, K, Nmat;
    if (idx < 524288) { m = (int)(idx >> 16); local = (int)(idx & 65535); K = 256; Nmat = 256; }
    else {
        const long j = idx - 524288;
        const int m2 = (int)(j >> 18); local = (int)(j & 262143);
        m = 8 + m2;
        if (m2 == 0 || m2 == 2) { K = 256; Nmat = 1024; } else { K = 1024; Nmat = 256; }
    }
    const int k = local / Nmat, n = local - k * Nmat;
    pa.dst[m][(size_t)n * K + k] = f2b(ldx(pa.src[m], local, isb));
}

// ---------------------------------------------------------------------------
// mgqkv: merged node-QKV (MODE0) + edge-QKV (MODE7).  Verified r16 inner loop.
// grid (6, nby + edge_by).  by < nby -> node (A=x16, C=QKVN[N,768]);
// else edge (A=lgx16; seg0 -> QE +bias+xg[sidx]; seg1 -> KVE.k; seg2 ->
// KVE.v +xg[didx]).
// ---------------------------------------------------------------------------
__global__ __launch_bounds__(256) void mgqkv(
    const bf16* __restrict__ An, int Mn,
    const bf16* __restrict__ Ae, int Me,
    const bf16* __restrict__ nBq, const bf16* __restrict__ nBk, const bf16* __restrict__ nBv,
    const void* __restrict__ nbias,
    const bf16* __restrict__ eBq, const bf16* __restrict__ eBk, const bf16* __restrict__ eBv,
    const void* __restrict__ ebias,
    const bf16* __restrict__ xg,
    const int* __restrict__ sidx, const int* __restrict__ didx,
    bf16* __restrict__ Cn, bf16* __restrict__ Cq, bf16* __restrict__ Ckv,
    int nby, const int* __restrict__ dflag)
{
    const bool isb = (*dflag != 0);
    __shared__ __align__(16) bf16 Al[128 * 64];
    __shared__ __align__(16) bf16 Bl[128 * 64];
    __shared__ float biasl[128];

    const int tid = threadIdx.x;
    const int lane = tid & 63, wave = tid >> 6;
    const int l15 = lane & 15, g = lane >> 4;
    const int t4 = l15 & 3, qd = l15 >> 2;
    const int wr = wave >> 1, wc = wave & 1;

    const int nwgx = gridDim.x;
    int wg = xcd_swz(blockIdx.y * nwgx + blockIdx.x, nwgx * gridDim.y);
    const int by = wg / nwgx, bx = wg % nwgx;
    const bool nodeb = (by < nby);
    const int rb = (nodeb ? by : (by - nby)) * 128;
    const int cb = bx * 128;
    const int M = nodeb ? Mn : Me;
    const bf16* A = nodeb ? An : Ae;
    const int seg = cb >> 8;
    const bf16* Bsel = nodeb ? ((seg == 0) ? nBq : ((seg == 1) ? nBk : nBv))
                             : ((seg == 0) ? eBq : ((seg == 1) ? eBk : eBv));
    const void* bias = nodeb ? nbias : ebias;
    const int cloc = cb & 255;

    if (tid < 128) {
        const int gc = cb + tid;
        biasl[tid] = (gc < 256) ? ldx(bias, gc, isb) : 0.f;
    }

    const int sp = lane & 7, sr8 = lane >> 3;
    int rls[4]; long arows[4];
    #pragma unroll
    for (int j = 0; j < 4; j++) {
        const int rl = wave * 32 + j * 8 + sr8;
        rls[j] = rl;
        const int gm = rb + rl;
        arows[j] = (gm < M) ? gm : (M - 1);
    }

    float4v acc[4][4];
    #pragma unroll
    for (int i = 0; i < 4; i++)
        #pragma unroll
        for (int j = 0; j < 4; j++)
            acc[i][j] = (float4v){0.f, 0.f, 0.f, 0.f};

    for (int k0 = 0; k0 < 256; k0 += 64) {
        #pragma unroll
        for (int j = 0; j < 4; j++) {
            const int rl = rls[j];
            const int pp = sp ^ (rl & 7);
            gl16(A + arows[j] * 256 + k0 + pp * 8,                 Al + rl * 64 + sp * 8);
            gl16(Bsel + (size_t)(cloc + rl) * 256 + k0 + pp * 8,   Bl + rl * 64 + sp * 8);
        }
        __syncthreads();
        #pragma unroll
        for (int ks = 0; ks < 2; ks++) {
            short8v av[4], bv[4];
            #pragma unroll
            for (int mi = 0; mi < 4; mi++) {
                const int row = wr * 64 + mi * 16 + l15;
                const int cp = (ks * 4 + g) ^ (row & 7);
                av[mi] = *reinterpret_cast<const short8v*>(&Al[row * 64 + cp * 8]);
            }
            #pragma unroll
            for (int ni = 0; ni < 4; ni++) {
                const int row = wc * 64 + ni * 16 + l15;
                const int cp = (ks * 4 + g) ^ (row & 7);
                bv[ni] = *reinterpret_cast<const short8v*>(&Bl[row * 64 + cp * 8]);
            }
            #pragma unroll
            for (int mi = 0; mi < 4; mi++)
                #pragma unroll
                for (int ni = 0; ni < 4; ni++)
                    acc[mi][ni] = __builtin_amdgcn_mfma_f32_16x16x32_bf16(
                        av[mi], bv[ni], acc[mi][ni], 0, 0, 0);
        }
        __syncthreads();
    }

    #pragma unroll
    for (int mi = 0; mi < 4; mi++) {
        const int grow = rb + wr * 64 + mi * 16 + g * 4 + t4;
        const bool ok = (grow < M);
        int s5 = 0, d5 = 0;
        if (!nodeb && ok) {
            if (cb < 256) s5 = sidx[grow];
            else if (cb >= 512) d5 = didx[grow];
        }
        #pragma unroll
        for (int ni = 0; ni < 4; ni++) {
            float a[4];
            #pragma unroll
            for (int r = 0; r < 4; r++) a[r] = acc[mi][ni][r];
            quadT(a, t4);
            if (!ok) continue;
            const int ct = wc * 64 + ni * 16 + qd * 4;
            const int gc = cb + ct;
            if (nodeb) {
                if (gc < 256) {
                    #pragma unroll
                    for (int u = 0; u < 4; u++) a[u] += biasl[ct + u];
                }
                U4 o;
                #pragma unroll
                for (int u = 0; u < 4; u++) o.h[u] = f2b(a[u]);
                *reinterpret_cast<int2*>(&Cn[(size_t)grow * 768 + gc]) = o.v;
            } else {
                if (gc < 256) {
                    U4 xx; xx.v = *reinterpret_cast<const int2*>(&xg[(size_t)s5 * 256 + gc]);
                    #pragma unroll
                    for (int u = 0; u < 4; u++) a[u] += biasl[ct + u] + b2f(xx.h[u]);
                    U4 o;
                    #pragma unroll
                    for (int u = 0; u < 4; u++) o.h[u] = f2b(a[u]);
                    *reinterpret_cast<int2*>(&Cq[(size_t)grow * 256 + gc]) = o.v;
                } else {
                    if (gc >= 512) {
                        U4 xx; xx.v = *reinterpret_cast<const int2*>(&xg[(size_t)d5 * 256 + (gc - 512)]);
                        #pragma unroll
                        for (int u = 0; u < 4; u++) a[u] += b2f(xx.h[u]);
                    }
                    U4 o;
                    #pragma unroll
                    for (int u = 0; u < 4; u++) o.h[u] = f2b(a[u]);
                    *reinterpret_cast<int2*>(&Ckv[(size_t)grow * 512 + (gc - 256)]) = o.v;
                }
            }
        }
    }
}

// ---------------------------------------------------------------------------
// mgattn: merged node+edge attention (vectorized, verified r14/r16 bodies).
// blocks [0,nab): node (4 nodes/block); [nab,..): edge (4 dsts/block).
// ---------------------------------------------------------------------------
__global__ __launch_bounds__(256) void mgattn(
    const bf16* __restrict__ QKV, const int* __restrict__ lsrc,
    const bf16* __restrict__ lgx16, bf16* __restrict__ ONo,
    const bf16* __restrict__ QE, const bf16* __restrict__ KVE,
    const int* __restrict__ lgsrc, bf16* __restrict__ OEo,
    int nab)
{
    const int w = threadIdx.x >> 6, lane = threadIdx.x & 63;
    const int c4 = lane * 4;
    if (blockIdx.x < nab) {
        const int d = blockIdx.x * 4 + w;
        if (d >= N_NODES) return;
        U4 uq; uq.v = *reinterpret_cast<const int2*>(&QKV[(size_t)d * 768 + c4]);
        float q[4];
        #pragma unroll
        for (int u = 0; u < 4; u++) q[u] = b2f(uq.h[u]);
        float acc[4] = {0.f, 0.f, 0.f, 0.f};
        float z = 0.f;
        for (int j = 0; j < 16; j++) {
            const int i = d + j * N_NODES;
            const int s = lsrc[i];
            U4 ue; ue.v = *reinterpret_cast<const int2*>(&lgx16[(size_t)i * 256 + c4]);
            U4 uk; uk.v = *reinterpret_cast<const int2*>(&QKV[(size_t)s * 768 + 256 + c4]);
            U4 uv; uv.v = *reinterpret_cast<const int2*>(&QKV[(size_t)s * 768 + 512 + c4]);
            float e[4], p = 0.f;
            #pragma unroll
            for (int u = 0; u < 4; u++) {
                e[u] = b2f(ue.h[u]);
                p += (b2f(uk.h[u]) + e[u]) * q[u];
            }
            p += __shfl_xor(p, 4); p += __shfl_xor(p, 2); p += __shfl_xor(p, 1);
            const float sc = expf(fminf(fmaxf(p * 0.17677669529663687f, -10.f), 10.f));
            #pragma unroll
            for (int u = 0; u < 4; u++) acc[u] += (b2f(uv.h[u]) + e[u]) * sc;
            z += sc;
        }
        U4 o;
        const float iz = 1.f / z;
        #pragma unroll
        for (int u = 0; u < 4; u++) o.h[u] = f2b(acc[u] * iz);
        *reinterpret_cast<int2*>(&ONo[(size_t)d * 256 + c4]) = o.v;
    } else {
        const int b = (blockIdx.x - nab) * 4 + w;
        if (b >= E_EDGES) return;
        U4 uq; uq.v = *reinterpret_cast<const int2*>(&QE[(size_t)b * 256 + c4]);
        float q[4];
        #pragma unroll
        for (int u = 0; u < 4; u++) q[u] = b2f(uq.h[u]);
        float acc[4] = {0.f, 0.f, 0.f, 0.f};
        float z = 0.f;
        #pragma unroll
        for (int j = 0; j < 2; j++) {
            const int s = lgsrc[b + j * E_EDGES];
            const size_t kr = (size_t)s * 512;
            U4 uk; uk.v = *reinterpret_cast<const int2*>(&KVE[kr + c4]);
            U4 uv; uv.v = *reinterpret_cast<const int2*>(&KVE[kr + 256 + c4]);
            float p = 0.f;
            #pragma unroll
            for (int u = 0; u < 4; u++) p += b2f(uk.h[u]) * q[u];
            p += __shfl_xor(p, 4); p += __shfl_xor(p, 2); p += __shfl_xor(p, 1);
            const float sc = expf(fminf(fmaxf(p * 0.17677669529663687f, -10.f), 10.f));
            #pragma unroll
            for (int u = 0; u < 4; u++) acc[u] += b2f(uv.h[u]) * sc;
            z += sc;
        }
        U4 o;
        const float iz = 1.f / z;
        #pragma unroll
        for (int u = 0; u < 4; u++) o.h[u] = f2b(acc[u] * iz);
        *reinterpret_cast<int2*>(&OEo[(size_t)b * 256 + c4]) = o.v;
    }
}

// ---------------------------------------------------------------------------
// mgwoln: merged node+edge Wo+bias+resid -> LN -> bf16 C.  (mgln<8> body,
// verified r11-r16.)  512 thr, 8 waves (2x4), BM=128, BN=256, K=256.
// ---------------------------------------------------------------------------
__global__ __launch_bounds__(512) void mgwoln(
    const bf16* __restrict__ An, int Mn,
    const bf16* __restrict__ Ae, int Me,
    const bf16* __restrict__ nBt, const void* __restrict__ nbias,
    const bf16* __restrict__ nresid, const void* __restrict__ nlng, const void* __restrict__ nlnb,
    bf16* __restrict__ Cn,
    const bf16* __restrict__ eBt, const void* __restrict__ ebias,
    const bf16* __restrict__ eresid, const void* __restrict__ elng, const void* __restrict__ elnb,
    bf16* __restrict__ Ce,
    int nby, const int* __restrict__ dflag)
{
    const bool isb = (*dflag != 0);
    __shared__ __align__(16) bf16 Al[128 * 64];   // 16KB (Ps overlay)
    __shared__ __align__(16) bf16 Bl[256 * 64];   // 32KB (Mr/Rsd overlay)
    __shared__ float biasl[256];
    __shared__ float lngl[256];
    __shared__ float lnbl[256];

    const int tid = threadIdx.x;
    const int lane = tid & 63, wave = tid >> 6;
    const int l15 = lane & 15, g = lane >> 4;
    const int t4 = l15 & 3, qd = l15 >> 2;
    const int wr = wave >> 2, wc = wave & 3;   // 2 x 4 wave grid

    const int wg = xcd_swz(blockIdx.y, gridDim.y);
    const bool nodeb = (wg < nby);
    const int rb = (nodeb ? wg : (wg - nby)) * 128;
    const int M = nodeb ? Mn : Me;
    const bf16* A = nodeb ? An : Ae;
    const bf16* Bt = nodeb ? nBt : eBt;
    const void* bias = nodeb ? nbias : ebias;
    const bf16* resid = nodeb ? nresid : eresid;
    const void* lng = nodeb ? nlng : elng;
    const void* lnb = nodeb ? nlnb : elnb;
    bf16* C = nodeb ? Cn : Ce;

    if (tid < 256) {
        biasl[tid] = ldx(bias, tid, isb);
        lngl[tid]  = ldx(lng,  tid, isb);
        lnbl[tid]  = ldx(lnb,  tid, isb);
    }

    const int sp = lane & 7, sr8 = lane >> 3;
    int rlA[2]; long arA[2];
    #pragma unroll
    for (int j = 0; j < 2; j++) {
        const int rl = wave * 16 + j * 8 + sr8;
        rlA[j] = rl;
        const int gm = rb + rl;
        arA[j] = (gm < M) ? gm : (M - 1);
    }
    int rlB[4];
    #pragma unroll
    for (int j = 0; j < 4; j++) rlB[j] = wave * 32 + j * 8 + sr8;

    float4v acc[4][4];
    #pragma unroll
    for (int i = 0; i < 4; i++)
        #pragma unroll
        for (int j = 0; j < 4; j++)
            acc[i][j] = (float4v){0.f, 0.f, 0.f, 0.f};

    for (int k0 = 0; k0 < 256; k0 += 64) {
        #pragma unroll
        for (int j = 0; j < 2; j++) {
            const int pp = sp ^ (rlA[j] & 7);
            gl16(A + arA[j] * 256 + k0 + pp * 8, Al + rlA[j] * 64 + sp * 8);
        }
        #pragma unroll
        for (int j = 0; j < 4; j++) {
            const int pp = sp ^ (rlB[j] & 7);
            gl16(Bt + (size_t)rlB[j] * 256 + k0 + pp * 8, Bl + rlB[j] * 64 + sp * 8);
        }
        __syncthreads();
        #pragma unroll
        for (int ks = 0; ks < 2; ks++) {
            short8v av[4], bv[4];
            #pragma unroll
            for (int mi = 0; mi < 4; mi++) {
                const int row = wr * 64 + mi * 16 + l15;
                const int cp = (ks * 4 + g) ^ (row & 7);
                av[mi] = *reinterpret_cast<const short8v*>(&Al[row * 64 + cp * 8]);
            }
            #pragma unroll
            for (int ni = 0; ni < 4; ni++) {
                const int row = wc * 64 + ni * 16 + l15;
                const int cp = (ks * 4 + g) ^ (row & 7);
                bv[ni] = *reinterpret_cast<const short8v*>(&Bl[row * 64 + cp * 8]);
            }
            #pragma unroll
            for (int mi = 0; mi < 4; mi++)
                #pragma unroll
                for (int ni = 0; ni < 4; ni++)
                    acc[mi][ni] = __builtin_amdgcn_mfma_f32_16x16x32_bf16(
                        av[mi], bv[ni], acc[mi][ni], 0, 0, 0);
        }
        __syncthreads();
    }

    float s1[4] = {0.f,0.f,0.f,0.f}, s2[4] = {0.f,0.f,0.f,0.f};
    #pragma unroll
    for (int mi = 0; mi < 4; mi++) {
        const int grow = rb + wr * 64 + mi * 16 + g * 4 + t4;
        const bool ok = (grow < M);
        #pragma unroll
        for (int ni = 0; ni < 4; ni++) {
            float a[4];
            #pragma unroll
            for (int r = 0; r < 4; r++) a[r] = acc[mi][ni][r];
            quadT(a, t4);
            const int ct = wc * 64 + ni * 16 + qd * 4;
            U4 rr; rr.v = make_int2(0, 0);
            if (ok) rr.v = *reinterpret_cast<const int2*>(&resid[(size_t)grow * 256 + ct]);
            #pragma unroll
            for (int u = 0; u < 4; u++) {
                a[u] += biasl[ct + u] + b2f(rr.h[u]);
                s1[mi] += a[u];
                s2[mi] += a[u] * a[u];
                acc[mi][ni][u] = a[u];
            }
        }
    }
    float* Ps1 = (float*)Al;          // [16][128]
    float* Ps2 = Ps1 + 2048;
    #pragma unroll
    for (int mi = 0; mi < 4; mi++) {
        const int rowl = wr * 64 + mi * 16 + g * 4 + t4;
        Ps1[(wc * 4 + qd) * 128 + rowl] = s1[mi];
        Ps2[(wc * 4 + qd) * 128 + rowl] = s2[mi];
    }
    __syncthreads();
    float* Mr  = (float*)Bl;
    float* Rsd = Mr + 128;
    if (tid < 128) {
        float a1 = 0.f, a2 = 0.f;
        #pragma unroll
        for (int k = 0; k < 16; k++) { a1 += Ps1[k * 128 + tid]; a2 += Ps2[k * 128 + tid]; }
        const float mn = a1 * (1.f / 256.f);
        const float var = a2 * (1.f / 256.f) - mn * mn;
        Mr[tid] = mn;
        Rsd[tid] = rsqrtf(fmaxf(var, 0.f) + 1e-5f);
    }
    __syncthreads();
    #pragma unroll
    for (int mi = 0; mi < 4; mi++) {
        const int rowl = wr * 64 + mi * 16 + g * 4 + t4;
        const int grow = rb + rowl;
        if (grow >= M) continue;
        const float mn = Mr[rowl], rd = Rsd[rowl];
        #pragma unroll
        for (int ni = 0; ni < 4; ni++) {
            const int ct = wc * 64 + ni * 16 + qd * 4;
            U4 ob;
            #pragma unroll
            for (int u = 0; u < 4; u++)
                ob.h[u] = f2b((acc[mi][ni][u] - mn) * rd * lngl[ct + u] + lnbl[ct + u]);
            *reinterpret_cast<int2*>(&C[(size_t)grow * 256 + ct]) = ob.v;
        }
    }
}

// ---------------------------------------------------------------------------
// mgffn1: merged node+edge FFN1 relu(+bias), K=256, NC=1024.  (mg<3> body.)
// ---------------------------------------------------------------------------
__global__ __launch_bounds__(256) void mgffn1(
    const bf16* __restrict__ An, int Mn,
    const bf16* __restrict__ Ae, int Me,
    const bf16* __restrict__ nBt, const void* __restrict__ nbias, bf16* __restrict__ Cn,
    const bf16* __restrict__ eBt, const void* __restrict__ ebias, bf16* __restrict__ Ce,
    int nby, const int* __restrict__ dflag)
{
    const bool isb = (*dflag != 0);
    __shared__ __align__(16) bf16 Al[128 * 64];
    __shared__ __align__(16) bf16 Bl[128 * 64];
    __shared__ float biasl[128];

    const int tid = threadIdx.x;
    const int lane = tid & 63, wave = tid >> 6;
    const int l15 = lane & 15, g = lane >> 4;
    const int t4 = l15 & 3, qd = l15 >> 2;
    const int wr = wave >> 1, wc = wave & 1;

    const int nwgx = gridDim.x;   // 8
    int wg = xcd_swz(blockIdx.y * nwgx + blockIdx.x, nwgx * gridDim.y);
    const int by = wg / nwgx, bx = wg % nwgx;
    const bool nodeb = (by < nby);
    const int rb = (nodeb ? by : (by - nby)) * 128;
    const int cb = bx * 128;
    const int M = nodeb ? Mn : Me;
    const bf16* A = nodeb ? An : Ae;
    const bf16* Bt = nodeb ? nBt : eBt;
    const void* bias = nodeb ? nbias : ebias;
    bf16* C = nodeb ? Cn : Ce;

    if (tid < 128) biasl[tid] = ldx(bias, cb + tid, isb);

    const int sp = lane & 7, sr8 = lane >> 3;
    int rls[4]; long arows[4];
    #pragma unroll
    for (int j = 0; j < 4; j++) {
        const int rl = wave * 32 + j * 8 + sr8;
        rls[j] = rl;
        const int gm = rb + rl;
        arows[j] = (gm < M) ? gm : (M - 1);
    }

    float4v acc[4][4];
    #pragma unroll
    for (int i = 0; i < 4; i++)
        #pragma unroll
        for (int j = 0; j < 4; j++)
            acc[i][j] = (float4v){0.f, 0.f, 0.f, 0.f};

    for (int k0 = 0; k0 < 256; k0 += 64) {
        #pragma unroll
        for (int j = 0; j < 4; j++) {
            const int rl = rls[j];
            const int pp = sp ^ (rl & 7);
            gl16(A + arows[j] * 256 + k0 + pp * 8,              Al + rl * 64 + sp * 8);
            gl16(Bt + (size_t)(cb + rl) * 256 + k0 + pp * 8,    Bl + rl * 64 + sp * 8);
        }
        __syncthreads();
        #pragma unroll
        for (int ks = 0; ks < 2; ks++) {
            short8v av[4], bv[4];
            #pragma unroll
            for (int mi = 0; mi < 4; mi++) {
                const int row = wr * 64 + mi * 16 + l15;
                const int cp = (ks * 4 + g) ^ (row & 7);
                av[mi] = *reinterpret_cast<const short8v*>(&Al[row * 64 + cp * 8]);
            }
            #pragma unroll
            for (int ni = 0; ni < 4; ni++) {
                const int row = wc * 64 + ni * 16 + l15;
                const int cp = (ks * 4 + g) ^ (row & 7);
                bv[ni] = *reinterpret_cast<const short8v*>(&Bl[row * 64 + cp * 8]);
            }
            #pragma unroll
            for (int mi = 0; mi < 4; mi++)
                #pragma unroll
                for (int ni = 0; ni < 4; ni++)
                    acc[mi][ni] = __builtin_amdgcn_mfma_f32_16x16x32_bf16(
                        av[mi], bv[ni], acc[mi][ni], 0, 0, 0);
        }
        __syncthreads();
    }

    #pragma unroll
    for (int mi = 0; mi < 4; mi++) {
        const int grow = rb + wr * 64 + mi * 16 + g * 4 + t4;
        const bool ok = (grow < M);
        #pragma unroll
        for (int ni = 0; ni < 4; ni++) {
            float a[4];
            #pragma unroll
            for (int r = 0; r < 4; r++) a[r] = acc[mi][ni][r];
            quadT(a, t4);
            if (!ok) continue;
            const int ct = wc * 64 + ni * 16 + qd * 4;
            U4 o;
            #pragma unroll
            for (int u = 0; u < 4; u++) o.h[u] = f2b(fmaxf(a[u] + biasl[ct + u], 0.f));
            *reinterpret_cast<int2*>(&C[(size_t)grow * 1024 + cb + ct]) = o.v;
        }
    }
}

// ---------------------------------------------------------------------------
// mgffn2: merged node+edge FFN2(+bias+resid) -> LN -> dtype-flex out.
// (mgln<9> body, K=1024.)  512 thr.
// ---------------------------------------------------------------------------
__global__ __launch_bounds__(512) void mgffn2(
    const bf16* __restrict__ An, int Mn,
    const bf16* __restrict__ Ae, int Me,
    const bf16* __restrict__ nBt, const void* __restrict__ nbias,
    const bf16* __restrict__ nresid, const void* __restrict__ nlng, const void* __restrict__ nlnb,
    long nobase,
    const bf16* __restrict__ eBt, const void* __restrict__ ebias,
    const bf16* __restrict__ eresid, const void* __restrict__ elng, const void* __restrict__ elnb,
    long eobase,
    void* __restrict__ outv,
    int nby, const int* __restrict__ dflag)
{
    const bool isb = (*dflag != 0);
    __shared__ __align__(16) bf16 Al[128 * 64];   // 16KB (Ps overlay)
    __shared__ __align__(16) bf16 Bl[256 * 64];   // 32KB (Mr/Rsd overlay)
    __shared__ float biasl[256];
    __shared__ float lngl[256];
    __shared__ float lnbl[256];

    const int tid = threadIdx.x;
    const int lane = tid & 63, wave = tid >> 6;
    const int l15 = lane & 15, g = lane >> 4;
    const int t4 = l15 & 3, qd = l15 >> 2;
    const int wr = wave >> 2, wc = wave & 3;   // 2 x 4 wave grid

    const int wg = xcd_swz(blockIdx.y, gridDim.y);
    const bool nodeb = (wg < nby);
    const int rb = (nodeb ? wg : (wg - nby)) * 128;
    const int M = nodeb ? Mn : Me;
    const bf16* A = nodeb ? An : Ae;
    const bf16* Bt = nodeb ? nBt : eBt;
    const void* bias = nodeb ? nbias : ebias;
    const bf16* resid = nodeb ? nresid : eresid;
    const void* lng = nodeb ? nlng : elng;
    const void* lnb = nodeb ? nlnb : elnb;
    const long obase = nodeb ? nobase : eobase;

    if (tid < 256) {
        biasl[tid] = ldx(bias, tid, isb);
        lngl[tid]  = ldx(lng,  tid, isb);
        lnbl[tid]  = ldx(lnb,  tid, isb);
    }

    const int sp = lane & 7, sr8 = lane >> 3;
    int rlA[2]; long arA[2];
    #pragma unroll
    for (int j = 0; j < 2; j++) {
        const int rl = wave * 16 + j * 8 + sr8;
        rlA[j] = rl;
        const int gm = rb + rl;
        arA[j] = (gm < M) ? gm : (M - 1);
    }
    int rlB[4];
    #pragma unroll
    for (int j = 0; j < 4; j++) rlB[j] = wave * 32 + j * 8 + sr8;

    float4v acc[4][4];
    #pragma unroll
    for (int i = 0; i < 4; i++)
        #pragma unroll
        for (int j = 0; j < 4; j++)
            acc[i][j] = (float4v){0.f, 0.f, 0.f, 0.f};

    for (int k0 = 0; k0 < 1024; k0 += 64) {
        #pragma unroll
        for (int j = 0; j < 2; j++) {
            const int pp = sp ^ (rlA[j] & 7);
            gl16(A + arA[j] * 1024 + k0 + pp * 8, Al + rlA[j] * 64 + sp * 8);
        }
        #pragma unroll
        for (int j = 0; j < 4; j++) {
            const int pp = sp ^ (rlB[j] & 7);
            gl16(Bt + (size_t)rlB[j] * 1024 + k0 + pp * 8, Bl + rlB[j] * 64 + sp * 8);
        }
        __syncthreads();
        #pragma unroll
        for (int ks = 0; ks < 2; ks++) {
            short8v av[4], bv[4];
            #pragma unroll
            for (int mi = 0; mi < 4; mi++) {
                const int row = wr * 64 + mi * 16 + l15;
                const int cp = (ks * 4 + g) ^ (row & 7);
                av[mi] = *reinterpret_cast<const short8v*>(&Al[row * 64 + cp * 8]);
            }
            #pragma unroll
            for (int ni = 0; ni < 4; ni++) {
                const int row = wc * 64 + ni * 16 + l15;
                const int cp = (ks * 4 + g) ^ (row & 7);
                bv[ni] = *reinterpret_cast<const short8v*>(&Bl[row * 64 + cp * 8]);
            }
            #pragma unroll
            for (int mi = 0; mi < 4; mi++)
                #pragma unroll
                for (int ni = 0; ni < 4; ni++)
                    acc[mi][ni] = __builtin_amdgcn_mfma_f32_16x16x32_bf16(
                        av[mi], bv[ni], acc[mi][ni], 0, 0, 0);
        }
        __syncthreads();
    }

    float s1[4] = {0.f,0.f,0.f,0.f}, s2[4] = {0.f,0.f,0.f,0.f};
    #pragma unroll
    for (int mi = 0; mi < 4; mi++) {
        const int grow = rb + wr * 64 + mi * 16 + g * 4 + t4;
        const bool ok = (grow < M);
        #pragma unroll
        for (int ni = 0; ni < 4; ni++) {
            float a[4];
            #pragma unroll
            for (int r = 0; r < 4; r++) a[r] = acc[mi][ni][r];
            quadT(a, t4);
            const int ct = wc * 64 + ni * 16 + qd * 4;
            U4 rr; rr.v = make_int2(0, 0);
            if (ok) rr.v = *reinterpret_cast<const int2*>(&resid[(size_t)grow * 256 + ct]);
            #pragma unroll
            for (int u = 0; u < 4; u++) {
                a[u] += biasl[ct + u] + b2f(rr.h[u]);
                s1[mi] += a[u];
                s2[mi] += a[u] * a[u];
                acc[mi][ni][u] = a[u];
            }
        }
    }
    float* Ps1 = (float*)Al;          // [16][128]
    float* Ps2 = Ps1 + 2048;
    #pragma unroll
    for (int mi = 0; mi < 4; mi++) {
        const int rowl = wr * 64 + mi * 16 + g * 4 + t4;
        Ps1[(wc * 4 + qd) * 128 + rowl] = s1[mi];
        Ps2[(wc * 4 + qd) * 128 + rowl] = s2[mi];
    }
    __syncthreads();
    float* Mr  = (float*)Bl;
    float* Rsd = Mr + 128;
    if (tid < 128) {
        float a1 = 0.f, a2 = 0.f;
        #pragma unroll
        for (int k = 0; k < 16; k++) { a1 += Ps1[k * 128 + tid]; a2 += Ps2[k * 128 + tid]; }
        const float mn = a1 * (1.f / 256.f);
        const float var = a2 * (1.f / 256.f) - mn * mn;
        Mr[tid] = mn;
        Rsd[tid] = rsqrtf(fmaxf(var, 0.f) + 1e-5f);
    }
    __syncthreads();
    #pragma unroll
    for (int mi = 0; mi < 4; mi++) {
        const int rowl = wr * 64 + mi * 16 + g * 4 + t4;
        const int grow = rb + rowl;
        if (grow >= M) continue;
        const float mn = Mr[rowl], rd = Rsd[rowl];
        #pragma unroll
        for (int ni = 0; ni < 4; ni++) {
            const int ct = wc * 64 + ni * 16 + qd * 4;
            float o[4];
            #pragma unroll
            for (int u = 0; u < 4; u++)
                o[u] = (acc[mi][ni][u] - mn) * rd * lngl[ct + u] + lnbl[ct + u];
            if (isb) {
                U4 ob;
                #pragma unroll
                for (int u = 0; u < 4; u++) ob.h[u] = f2b(o[u]);
                *reinterpret_cast<int2*>((bf16*)outv + obase + (size_t)grow * 256 + ct) = ob.v;
            } else {
                float4 f4 = make_float4(o[0], o[1], o[2], o[3]);
                *reinterpret_cast<float4*>((float*)outv + obase + (size_t)grow * 256 + ct) = f4;
            }
        }
    }
}

// ---------------------------------------------------------------------------
extern "C" void kernel_launch(void* const* d_in, const int* in_sizes, int n_in,
                              void* d_out, int out_size, void* d_ws, size_t ws_size,
                              hipStream_t stream)
{
    const void* x   = d_in[0];
    const void* lgx = d_in[1];
    const int* local_src = (const int*)d_in[3];
    const int* lg_src    = (const int*)d_in[5];
    const int* src_ids   = (const int*)d_in[7];
    const int* dst_ids   = (const int*)d_in[8];

    const void *nWq = d_in[9],  *nbq = d_in[10], *nWk = d_in[11], *nWv = d_in[12],
               *nWo = d_in[13], *nbo = d_in[14], *nln1g = d_in[15], *nln1b = d_in[16],
               *nW1 = d_in[17], *nb1 = d_in[18], *nW2 = d_in[19], *nb2 = d_in[20],
               *nln2g = d_in[21], *nln2b = d_in[22];
    const void *eWq = d_in[23], *ebq = d_in[24], *eWk = d_in[25], *eWv = d_in[26],
               *eWo = d_in[27], *ebo = d_in[28], *eln1g = d_in[29], *eln1b = d_in[30],
               *eW1 = d_in[31], *eb1 = d_in[32], *eW2 = d_in[33], *eb2 = d_in[34],
               *eln2g = d_in[35], *eln2b = d_in[36];

    const dim3 blk(256);
    const dim3 blk2(512);

    // ===== ws layout (all bytes):
    // dflag 256 | packs 3,145,728 | x16 5.12M | lgx16 81.92M | KVE 163.84M |
    // QE 81.92M | QKVN 15.36M | ON 5.12M | HN 5.12M | FN 20.48M |
    // OE 81.92M | HE 81.92M | FE chunk (CH x 2048 B)
    int* dflag = (int*)d_ws;
    detect_dtype<<<1, 64, 0, stream>>>((const unsigned short*)x, dflag);

    bf16* pk = (bf16*)((char*)d_ws + 256);
    bf16 *pnWq = pk,            *pnWk = pk + 65536,   *pnWv = pk + 131072,
         *pnWo = pk + 196608,   *peWq = pk + 262144,  *peWk = pk + 327680,
         *peWv = pk + 393216,   *peWo = pk + 458752,
         *pnW1 = pk + 524288,   *pnW2 = pk + 786432,
         *peW1 = pk + 1048576,  *peW2 = pk + 1310720;
    bf16* x16   = pk + 1572864;                        // 2,560,000 elems
    bf16* lgx16 = x16 + 2560000;                       // 40,960,000
    bf16* KVE   = lgx16 + 40960000;                    // 81,920,000
    bf16* QE    = KVE + 81920000;                      // 40,960,000
    bf16* QKVN  = QE + 40960000;                       // 7,680,000
    bf16* ON    = QKVN + 7680000;                      // 2,560,000
    bf16* HN    = ON + 2560000;                        // 2,560,000
    bf16* FN    = HN + 2560000;                        // 10,240,000
    bf16* OE    = FN + 10240000;                       // 40,960,000
    bf16* HE    = OE + 40960000;                       // 40,960,000
    bf16* FE    = HE + 40960000;                       // CH x 1024

    cvt_bf16<<<1250,  blk, 0, stream>>>(x,   x16,   (long)N_NODES * 32, dflag);
    cvt_bf16<<<20000, blk, 0, stream>>>(lgx, lgx16, (long)E_EDGES * 32, dflag);

    PackArgs pa;
    pa.src[0] = nWq; pa.src[1] = nWk; pa.src[2] = nWv; pa.src[3] = nWo;
    pa.src[4] = eWq; pa.src[5] = eWk; pa.src[6] = eWv; pa.src[7] = eWo;
    pa.src[8] = nW1; pa.src[9] = nW2; pa.src[10] = eW1; pa.src[11] = eW2;
    pa.dst[0] = pnWq; pa.dst[1] = pnWk; pa.dst[2] = pnWv; pa.dst[3] = pnWo;
    pa.dst[4] = peWq; pa.dst[5] = peWk; pa.dst[6] = peWv; pa.dst[7] = peWo;
    pa.dst[8] = pnW1; pa.dst[9] = pnW2; pa.dst[10] = peW1; pa.dst[11] = peW2;
    pack_all<<<6144, blk, 0, stream>>>(pa, dflag);

    const int nby  = (N_NODES + 127) / 128;   // 79
    const int eby  = (E_EDGES + 127) / 128;   // 1250

    // chunk size for FE
    const size_t fixedB = 256 + 3145728
        + (size_t)2 * (2560000 + 40960000 + 81920000 + 40960000
                       + 7680000 + 2560000 + 2560000 + 10240000
                       + 40960000 + 40960000);
    long CH = 128;
    if (ws_size > fixedB) {
        CH = (long)(((ws_size - fixedB) / 2048) / 128 * 128);
        if (CH > E_EDGES) CH = E_EDGES;
        if (CH < 128) CH = 128;
    }

    // stage 1: merged QKV (node + edge)
    mgqkv<<<dim3(6, nby + eby), blk, 0, stream>>>(
        x16, N_NODES, lgx16, E_EDGES,
        pnWq, pnWk, pnWv, nbq,
        peWq, peWk, peWv, ebq,
        x16, src_ids, dst_ids,
        QKVN, QE, KVE, nby, dflag);

    // stage 2: merged attention
    const int nab = (N_NODES + 3) / 4;        // 2500
    const int eab = (E_EDGES + 3) / 4;        // 40000
    mgattn<<<nab + eab, blk, 0, stream>>>(
        QKVN, local_src, lgx16, ON, QE, KVE, lg_src, OE, nab);

    // stage 3: merged Wo + LN1
    mgwoln<<<dim3(1, nby + eby), blk2, 0, stream>>>(
        ON, N_NODES, OE, E_EDGES,
        pnWo, nbo, x16, nln1g, nln1b, HN,
        peWo, ebo, lgx16, eln1g, eln1b, HE,
        nby, dflag);

    // stages 4-5: FFN (node folded into chunk 0)
    for (long r0 = 0; r0 < E_EDGES; r0 += CH) {
        const int rows = (int)(((E_EDGES - r0) < CH) ? (E_EDGES - r0) : CH);
        const int gm = (rows + 127) / 128;
        const int nb = (r0 == 0) ? nby : 0;

        mgffn1<<<dim3(8, nb + gm), blk, 0, stream>>>(
            HN, N_NODES, HE + (size_t)r0 * 256, rows,
            pnW1, nb1, FN,
            peW1, eb1, FE,
            nb, dflag);
        mgffn2<<<dim3(1, nb + gm), blk2, 0, stream>>>(
            FN, N_NODES, FE, rows,
            pnW2, nb2, HN, nln2g, nln2b, 0L,
            peW2, eb2, HE + (size_t)r0 * 256, eln2g, eln2b,
            (long)N_NODES * 256 + r0 * 256,
            d_out, nb, dflag);
    }
}

// Round 18
// 954.246 us; speedup vs baseline: 1.2738x; 1.0348x over previous
//
#include <hip/hip_runtime.h>
#include <hip/hip_bf16.h>

typedef __hip_bfloat16 bf16;
typedef __attribute__((ext_vector_type(8))) short short8v;
typedef __attribute__((ext_vector_type(4))) float float4v;

#define N_NODES 10000
#define E_EDGES 160000

__device__ __forceinline__ float b2f(bf16 v){ return __bfloat162float(v); }
__device__ __forceinline__ bf16 f2b(float v){ return __float2bfloat16(v); }

union U8 { int4 v; bf16 h[8]; };
union U4 { int2 v; bf16 h[4]; };

// ---- dtype-flexible external accessors (flag: 1 = bf16, 0 = f32) ----------
__device__ __forceinline__ float ldx(const void* p, size_t i, bool isb){
    return isb ? b2f(((const bf16*)p)[i]) : ((const float*)p)[i];
}
__device__ __forceinline__ void ld8(const void* p, size_t i, bool isb, float* o){
    if (isb) {
        U8 u; u.v = *reinterpret_cast<const int4*>((const bf16*)p + i);
        #pragma unroll
        for (int j = 0; j < 8; j++) o[j] = b2f(u.h[j]);
    } else {
        const float4* q = reinterpret_cast<const float4*>((const float*)p + i);
        float4 a = q[0], b = q[1];
        o[0]=a.x; o[1]=a.y; o[2]=a.z; o[3]=a.w; o[4]=b.x; o[5]=b.y; o[6]=b.z; o[7]=b.w;
    }
}
__device__ __forceinline__ void stx(void* p, size_t i, bool isb, float v){
    if (isb) ((bf16*)p)[i] = f2b(v); else ((float*)p)[i] = v;
}

// async global->LDS, 16 B/lane (HW: LDS dest = wave-uniform base + lane*16)
typedef const __attribute__((address_space(1))) void* gas_p;
typedef __attribute__((address_space(3))) void* las_p;
__device__ __forceinline__ void gl16(const bf16* g, bf16* l){
    __builtin_amdgcn_global_load_lds((gas_p)g, (las_p)l, 16, 0, 0);
}

// 4x4 in-register transpose across 4 lanes (verified r9-r17)
__device__ __forceinline__ void quadT(float* a, int t){
    float x0 = (t & 1) ? a[0] : a[1];
    float y0 = __shfl_xor(x0, 1);
    if (t & 1) a[0] = y0; else a[1] = y0;
    float x1 = (t & 1) ? a[2] : a[3];
    float y1 = __shfl_xor(x1, 1);
    if (t & 1) a[2] = y1; else a[3] = y1;
    float x2 = (t & 2) ? a[0] : a[2];
    float y2 = __shfl_xor(x2, 2);
    if (t & 2) a[0] = y2; else a[2] = y2;
    float x3 = (t & 2) ? a[1] : a[3];
    float y3 = __shfl_xor(x3, 2);
    if (t & 2) a[1] = y3; else a[3] = y3;
}

// XCD-bijective swizzle of a linear workgroup id
__device__ __forceinline__ int xcd_swz(int wg, int nwg){
    const int q = nwg >> 3, r = nwg & 7;
    const int xcd = wg & 7, ix = wg >> 3;
    return (xcd < r ? xcd * (q + 1) : r * (q + 1) + (xcd - r) * q) + ix;
}

// ---------------------------------------------------------------------------
__global__ void detect_dtype(const unsigned short* __restrict__ xw, int* __restrict__ flag){
    const int lane = threadIdx.x;  // 64 threads
    int cnt = 0;
    for (int i = lane; i < 8192; i += 64) {
        const unsigned e = (xw[i] >> 7) & 0xFF;
        if (e == 0 || (e >= 100 && e <= 140)) cnt++;
    }
    #pragma unroll
    for (int off = 32; off >= 1; off >>= 1) cnt += __shfl_xor(cnt, off);
    if (lane == 0) *flag = (cnt >= 6554) ? 1 : 0;
}

// merged convert: groups [0, 320000) -> x16; [320000, 5440000) -> lgx16
__global__ __launch_bounds__(256) void cvt_both(
    const void* __restrict__ xin, const void* __restrict__ lgin,
    bf16* __restrict__ x16, bf16* __restrict__ lgx16,
    const int* __restrict__ dflag)
{
    const bool isb = (*dflag != 0);
    const long t = (long)blockIdx.x * 256 + threadIdx.x;
    if (t >= 5440000L) return;
    float f[8];
    if (t < 320000L) {
        ld8(xin, (size_t)t * 8, isb, f);
        U8 u;
        #pragma unroll
        for (int j = 0; j < 8; j++) u.h[j] = f2b(f[j]);
        *reinterpret_cast<int4*>(&x16[t * 8]) = u.v;
    } else {
        const long s = t - 320000L;
        ld8(lgin, (size_t)s * 8, isb, f);
        U8 u;
        #pragma unroll
        for (int j = 0; j < 8; j++) u.h[j] = f2b(f[j]);
        *reinterpret_cast<int4*>(&lgx16[s * 8]) = u.v;
    }
}

// ---------------------------------------------------------------------------
// pack_all: all 12 weight matrices -> transposed bf16 [Nmat][K] in one launch.
// ---------------------------------------------------------------------------
struct PackArgs { const void* src[12]; bf16* dst[12]; };
__global__ __launch_bounds__(256) void pack_all(PackArgs pa, const int* __restrict__ dflag){
    const bool isb = (*dflag != 0);
    const long idx = (long)blockIdx.x * 256 + threadIdx.x;
    if (idx >= 1572864) return;
    int m, local, K, Nmat;
    if (idx < 524288) { m = (int)(idx >> 16); local = (int)(idx & 65535); K = 256; Nmat = 256; }
    else {
        const long j = idx - 524288;
        const int m2 = (int)(j >> 18); local = (int)(j & 262143);
        m = 8 + m2;
        if (m2 == 0 || m2 == 2) { K = 256; Nmat = 1024; } else { K = 1024; Nmat = 256; }
    }
    const int k = local / Nmat, n = local - k * Nmat;
    pa.dst[m][(size_t)n * K + k] = f2b(ldx(pa.src[m], local, isb));
}

// ---------------------------------------------------------------------------
// mgqkv: merged node-QKV + edge-QKV (verified r17).
// ---------------------------------------------------------------------------
__global__ __launch_bounds__(256) void mgqkv(
    const bf16* __restrict__ An, int Mn,
    const bf16* __restrict__ Ae, int Me,
    const bf16* __restrict__ nBq, const bf16* __restrict__ nBk, const bf16* __restrict__ nBv,
    const void* __restrict__ nbias,
    const bf16* __restrict__ eBq, const bf16* __restrict__ eBk, const bf16* __restrict__ eBv,
    const void* __restrict__ ebias,
    const bf16* __restrict__ xg,
    const int* __restrict__ sidx, const int* __restrict__ didx,
    bf16* __restrict__ Cn, bf16* __restrict__ Cq, bf16* __restrict__ Ckv,
    int nby, const int* __restrict__ dflag)
{
    const bool isb = (*dflag != 0);
    __shared__ __align__(16) bf16 Al[128 * 64];
    __shared__ __align__(16) bf16 Bl[128 * 64];
    __shared__ float biasl[128];

    const int tid = threadIdx.x;
    const int lane = tid & 63, wave = tid >> 6;
    const int l15 = lane & 15, g = lane >> 4;
    const int t4 = l15 & 3, qd = l15 >> 2;
    const int wr = wave >> 1, wc = wave & 1;

    const int nwgx = gridDim.x;
    int wg = xcd_swz(blockIdx.y * nwgx + blockIdx.x, nwgx * gridDim.y);
    const int by = wg / nwgx, bx = wg % nwgx;
    const bool nodeb = (by < nby);
    const int rb = (nodeb ? by : (by - nby)) * 128;
    const int cb = bx * 128;
    const int M = nodeb ? Mn : Me;
    const bf16* A = nodeb ? An : Ae;
    const int seg = cb >> 8;
    const bf16* Bsel = nodeb ? ((seg == 0) ? nBq : ((seg == 1) ? nBk : nBv))
                             : ((seg == 0) ? eBq : ((seg == 1) ? eBk : eBv));
    const void* bias = nodeb ? nbias : ebias;
    const int cloc = cb & 255;

    if (tid < 128) {
        const int gc = cb + tid;
        biasl[tid] = (gc < 256) ? ldx(bias, gc, isb) : 0.f;
    }

    const int sp = lane & 7, sr8 = lane >> 3;
    int rls[4]; long arows[4];
    #pragma unroll
    for (int j = 0; j < 4; j++) {
        const int rl = wave * 32 + j * 8 + sr8;
        rls[j] = rl;
        const int gm = rb + rl;
        arows[j] = (gm < M) ? gm : (M - 1);
    }

    float4v acc[4][4];
    #pragma unroll
    for (int i = 0; i < 4; i++)
        #pragma unroll
        for (int j = 0; j < 4; j++)
            acc[i][j] = (float4v){0.f, 0.f, 0.f, 0.f};

    for (int k0 = 0; k0 < 256; k0 += 64) {
        #pragma unroll
        for (int j = 0; j < 4; j++) {
            const int rl = rls[j];
            const int pp = sp ^ (rl & 7);
            gl16(A + arows[j] * 256 + k0 + pp * 8,                 Al + rl * 64 + sp * 8);
            gl16(Bsel + (size_t)(cloc + rl) * 256 + k0 + pp * 8,   Bl + rl * 64 + sp * 8);
        }
        __syncthreads();
        #pragma unroll
        for (int ks = 0; ks < 2; ks++) {
            short8v av[4], bv[4];
            #pragma unroll
            for (int mi = 0; mi < 4; mi++) {
                const int row = wr * 64 + mi * 16 + l15;
                const int cp = (ks * 4 + g) ^ (row & 7);
                av[mi] = *reinterpret_cast<const short8v*>(&Al[row * 64 + cp * 8]);
            }
            #pragma unroll
            for (int ni = 0; ni < 4; ni++) {
                const int row = wc * 64 + ni * 16 + l15;
                const int cp = (ks * 4 + g) ^ (row & 7);
                bv[ni] = *reinterpret_cast<const short8v*>(&Bl[row * 64 + cp * 8]);
            }
            #pragma unroll
            for (int mi = 0; mi < 4; mi++)
                #pragma unroll
                for (int ni = 0; ni < 4; ni++)
                    acc[mi][ni] = __builtin_amdgcn_mfma_f32_16x16x32_bf16(
                        av[mi], bv[ni], acc[mi][ni], 0, 0, 0);
        }
        __syncthreads();
    }

    #pragma unroll
    for (int mi = 0; mi < 4; mi++) {
        const int grow = rb + wr * 64 + mi * 16 + g * 4 + t4;
        const bool ok = (grow < M);
        int s5 = 0, d5 = 0;
        if (!nodeb && ok) {
            if (cb < 256) s5 = sidx[grow];
            else if (cb >= 512) d5 = didx[grow];
        }
        #pragma unroll
        for (int ni = 0; ni < 4; ni++) {
            float a[4];
            #pragma unroll
            for (int r = 0; r < 4; r++) a[r] = acc[mi][ni][r];
            quadT(a, t4);
            if (!ok) continue;
            const int ct = wc * 64 + ni * 16 + qd * 4;
            const int gc = cb + ct;
            if (nodeb) {
                if (gc < 256) {
                    #pragma unroll
                    for (int u = 0; u < 4; u++) a[u] += biasl[ct + u];
                }
                U4 o;
                #pragma unroll
                for (int u = 0; u < 4; u++) o.h[u] = f2b(a[u]);
                *reinterpret_cast<int2*>(&Cn[(size_t)grow * 768 + gc]) = o.v;
            } else {
                if (gc < 256) {
                    U4 xx; xx.v = *reinterpret_cast<const int2*>(&xg[(size_t)s5 * 256 + gc]);
                    #pragma unroll
                    for (int u = 0; u < 4; u++) a[u] += biasl[ct + u] + b2f(xx.h[u]);
                    U4 o;
                    #pragma unroll
                    for (int u = 0; u < 4; u++) o.h[u] = f2b(a[u]);
                    *reinterpret_cast<int2*>(&Cq[(size_t)grow * 256 + gc]) = o.v;
                } else {
                    if (gc >= 512) {
                        U4 xx; xx.v = *reinterpret_cast<const int2*>(&xg[(size_t)d5 * 256 + (gc - 512)]);
                        #pragma unroll
                        for (int u = 0; u < 4; u++) a[u] += b2f(xx.h[u]);
                    }
                    U4 o;
                    #pragma unroll
                    for (int u = 0; u < 4; u++) o.h[u] = f2b(a[u]);
                    *reinterpret_cast<int2*>(&Ckv[(size_t)grow * 512 + (gc - 256)]) = o.v;
                }
            }
        }
    }
}

// ---------------------------------------------------------------------------
// mgattn: merged node+edge attention (verified r17).
// ---------------------------------------------------------------------------
__global__ __launch_bounds__(256) void mgattn(
    const bf16* __restrict__ QKV, const int* __restrict__ lsrc,
    const bf16* __restrict__ lgx16, bf16* __restrict__ ONo,
    const bf16* __restrict__ QE, const bf16* __restrict__ KVE,
    const int* __restrict__ lgsrc, bf16* __restrict__ OEo,
    int nab)
{
    const int w = threadIdx.x >> 6, lane = threadIdx.x & 63;
    const int c4 = lane * 4;
    if (blockIdx.x < nab) {
        const int d = blockIdx.x * 4 + w;
        if (d >= N_NODES) return;
        U4 uq; uq.v = *reinterpret_cast<const int2*>(&QKV[(size_t)d * 768 + c4]);
        float q[4];
        #pragma unroll
        for (int u = 0; u < 4; u++) q[u] = b2f(uq.h[u]);
        float acc[4] = {0.f, 0.f, 0.f, 0.f};
        float z = 0.f;
        for (int j = 0; j < 16; j++) {
            const int i = d + j * N_NODES;
            const int s = lsrc[i];
            U4 ue; ue.v = *reinterpret_cast<const int2*>(&lgx16[(size_t)i * 256 + c4]);
            U4 uk; uk.v = *reinterpret_cast<const int2*>(&QKV[(size_t)s * 768 + 256 + c4]);
            U4 uv; uv.v = *reinterpret_cast<const int2*>(&QKV[(size_t)s * 768 + 512 + c4]);
            float e[4], p = 0.f;
            #pragma unroll
            for (int u = 0; u < 4; u++) {
                e[u] = b2f(ue.h[u]);
                p += (b2f(uk.h[u]) + e[u]) * q[u];
            }
            p += __shfl_xor(p, 4); p += __shfl_xor(p, 2); p += __shfl_xor(p, 1);
            const float sc = expf(fminf(fmaxf(p * 0.17677669529663687f, -10.f), 10.f));
            #pragma unroll
            for (int u = 0; u < 4; u++) acc[u] += (b2f(uv.h[u]) + e[u]) * sc;
            z += sc;
        }
        U4 o;
        const float iz = 1.f / z;
        #pragma unroll
        for (int u = 0; u < 4; u++) o.h[u] = f2b(acc[u] * iz);
        *reinterpret_cast<int2*>(&ONo[(size_t)d * 256 + c4]) = o.v;
    } else {
        const int b = (blockIdx.x - nab) * 4 + w;
        if (b >= E_EDGES) return;
        U4 uq; uq.v = *reinterpret_cast<const int2*>(&QE[(size_t)b * 256 + c4]);
        float q[4];
        #pragma unroll
        for (int u = 0; u < 4; u++) q[u] = b2f(uq.h[u]);
        float acc[4] = {0.f, 0.f, 0.f, 0.f};
        float z = 0.f;
        #pragma unroll
        for (int j = 0; j < 2; j++) {
            const int s = lgsrc[b + j * E_EDGES];
            const size_t kr = (size_t)s * 512;
            U4 uk; uk.v = *reinterpret_cast<const int2*>(&KVE[kr + c4]);
            U4 uv; uv.v = *reinterpret_cast<const int2*>(&KVE[kr + 256 + c4]);
            float p = 0.f;
            #pragma unroll
            for (int u = 0; u < 4; u++) p += b2f(uk.h[u]) * q[u];
            p += __shfl_xor(p, 4); p += __shfl_xor(p, 2); p += __shfl_xor(p, 1);
            const float sc = expf(fminf(fmaxf(p * 0.17677669529663687f, -10.f), 10.f));
            #pragma unroll
            for (int u = 0; u < 4; u++) acc[u] += b2f(uv.h[u]) * sc;
            z += sc;
        }
        U4 o;
        const float iz = 1.f / z;
        #pragma unroll
        for (int u = 0; u < 4; u++) o.h[u] = f2b(acc[u] * iz);
        *reinterpret_cast<int2*>(&OEo[(size_t)b * 256 + c4]) = o.v;
    }
}

// ---------------------------------------------------------------------------
// mgwoln: merged node+edge Wo+bias+resid -> LN -> bf16 C (verified r17).
// ---------------------------------------------------------------------------
__global__ __launch_bounds__(512) void mgwoln(
    const bf16* __restrict__ An, int Mn,
    const bf16* __restrict__ Ae, int Me,
    const bf16* __restrict__ nBt, const void* __restrict__ nbias,
    const bf16* __restrict__ nresid, const void* __restrict__ nlng, const void* __restrict__ nlnb,
    bf16* __restrict__ Cn,
    const bf16* __restrict__ eBt, const void* __restrict__ ebias,
    const bf16* __restrict__ eresid, const void* __restrict__ elng, const void* __restrict__ elnb,
    bf16* __restrict__ Ce,
    int nby, const int* __restrict__ dflag)
{
    const bool isb = (*dflag != 0);
    __shared__ __align__(16) bf16 Al[128 * 64];   // 16KB (Ps overlay)
    __shared__ __align__(16) bf16 Bl[256 * 64];   // 32KB (Mr/Rsd overlay)
    __shared__ float biasl[256];
    __shared__ float lngl[256];
    __shared__ float lnbl[256];

    const int tid = threadIdx.x;
    const int lane = tid & 63, wave = tid >> 6;
    const int l15 = lane & 15, g = lane >> 4;
    const int t4 = l15 & 3, qd = l15 >> 2;
    const int wr = wave >> 2, wc = wave & 3;   // 2 x 4 wave grid

    const int wg = xcd_swz(blockIdx.y, gridDim.y);
    const bool nodeb = (wg < nby);
    const int rb = (nodeb ? wg : (wg - nby)) * 128;
    const int M = nodeb ? Mn : Me;
    const bf16* A = nodeb ? An : Ae;
    const bf16* Bt = nodeb ? nBt : eBt;
    const void* bias = nodeb ? nbias : ebias;
    const bf16* resid = nodeb ? nresid : eresid;
    const void* lng = nodeb ? nlng : elng;
    const void* lnb = nodeb ? nlnb : elnb;
    bf16* C = nodeb ? Cn : Ce;

    if (tid < 256) {
        biasl[tid] = ldx(bias, tid, isb);
        lngl[tid]  = ldx(lng,  tid, isb);
        lnbl[tid]  = ldx(lnb,  tid, isb);
    }

    const int sp = lane & 7, sr8 = lane >> 3;
    int rlA[2]; long arA[2];
    #pragma unroll
    for (int j = 0; j < 2; j++) {
        const int rl = wave * 16 + j * 8 + sr8;
        rlA[j] = rl;
        const int gm = rb + rl;
        arA[j] = (gm < M) ? gm : (M - 1);
    }
    int rlB[4];
    #pragma unroll
    for (int j = 0; j < 4; j++) rlB[j] = wave * 32 + j * 8 + sr8;

    float4v acc[4][4];
    #pragma unroll
    for (int i = 0; i < 4; i++)
        #pragma unroll
        for (int j = 0; j < 4; j++)
            acc[i][j] = (float4v){0.f, 0.f, 0.f, 0.f};

    for (int k0 = 0; k0 < 256; k0 += 64) {
        #pragma unroll
        for (int j = 0; j < 2; j++) {
            const int pp = sp ^ (rlA[j] & 7);
            gl16(A + arA[j] * 256 + k0 + pp * 8, Al + rlA[j] * 64 + sp * 8);
        }
        #pragma unroll
        for (int j = 0; j < 4; j++) {
            const int pp = sp ^ (rlB[j] & 7);
            gl16(Bt + (size_t)rlB[j] * 256 + k0 + pp * 8, Bl + rlB[j] * 64 + sp * 8);
        }
        __syncthreads();
        #pragma unroll
        for (int ks = 0; ks < 2; ks++) {
            short8v av[4], bv[4];
            #pragma unroll
            for (int mi = 0; mi < 4; mi++) {
                const int row = wr * 64 + mi * 16 + l15;
                const int cp = (ks * 4 + g) ^ (row & 7);
                av[mi] = *reinterpret_cast<const short8v*>(&Al[row * 64 + cp * 8]);
            }
            #pragma unroll
            for (int ni = 0; ni < 4; ni++) {
                const int row = wc * 64 + ni * 16 + l15;
                const int cp = (ks * 4 + g) ^ (row & 7);
                bv[ni] = *reinterpret_cast<const short8v*>(&Bl[row * 64 + cp * 8]);
            }
            #pragma unroll
            for (int mi = 0; mi < 4; mi++)
                #pragma unroll
                for (int ni = 0; ni < 4; ni++)
                    acc[mi][ni] = __builtin_amdgcn_mfma_f32_16x16x32_bf16(
                        av[mi], bv[ni], acc[mi][ni], 0, 0, 0);
        }
        __syncthreads();
    }

    float s1[4] = {0.f,0.f,0.f,0.f}, s2[4] = {0.f,0.f,0.f,0.f};
    #pragma unroll
    for (int mi = 0; mi < 4; mi++) {
        const int grow = rb + wr * 64 + mi * 16 + g * 4 + t4;
        const bool ok = (grow < M);
        #pragma unroll
        for (int ni = 0; ni < 4; ni++) {
            float a[4];
            #pragma unroll
            for (int r = 0; r < 4; r++) a[r] = acc[mi][ni][r];
            quadT(a, t4);
            const int ct = wc * 64 + ni * 16 + qd * 4;
            U4 rr; rr.v = make_int2(0, 0);
            if (ok) rr.v = *reinterpret_cast<const int2*>(&resid[(size_t)grow * 256 + ct]);
            #pragma unroll
            for (int u = 0; u < 4; u++) {
                a[u] += biasl[ct + u] + b2f(rr.h[u]);
                s1[mi] += a[u];
                s2[mi] += a[u] * a[u];
                acc[mi][ni][u] = a[u];
            }
        }
    }
    float* Ps1 = (float*)Al;          // [16][128]
    float* Ps2 = Ps1 + 2048;
    #pragma unroll
    for (int mi = 0; mi < 4; mi++) {
        const int rowl = wr * 64 + mi * 16 + g * 4 + t4;
        Ps1[(wc * 4 + qd) * 128 + rowl] = s1[mi];
        Ps2[(wc * 4 + qd) * 128 + rowl] = s2[mi];
    }
    __syncthreads();
    float* Mr  = (float*)Bl;
    float* Rsd = Mr + 128;
    if (tid < 128) {
        float a1 = 0.f, a2 = 0.f;
        #pragma unroll
        for (int k = 0; k < 16; k++) { a1 += Ps1[k * 128 + tid]; a2 += Ps2[k * 128 + tid]; }
        const float mn = a1 * (1.f / 256.f);
        const float var = a2 * (1.f / 256.f) - mn * mn;
        Mr[tid] = mn;
        Rsd[tid] = rsqrtf(fmaxf(var, 0.f) + 1e-5f);
    }
    __syncthreads();
    #pragma unroll
    for (int mi = 0; mi < 4; mi++) {
        const int rowl = wr * 64 + mi * 16 + g * 4 + t4;
        const int grow = rb + rowl;
        if (grow >= M) continue;
        const float mn = Mr[rowl], rd = Rsd[rowl];
        #pragma unroll
        for (int ni = 0; ni < 4; ni++) {
            const int ct = wc * 64 + ni * 16 + qd * 4;
            U4 ob;
            #pragma unroll
            for (int u = 0; u < 4; u++)
                ob.h[u] = f2b((acc[mi][ni][u] - mn) * rd * lngl[ct + u] + lnbl[ct + u]);
            *reinterpret_cast<int2*>(&C[(size_t)grow * 256 + ct]) = ob.v;
        }
    }
}

// ---------------------------------------------------------------------------
// mgffn1: merged node+edge FFN1 relu(+bias), K=256, NC=1024 (verified r17).
// ---------------------------------------------------------------------------
__global__ __launch_bounds__(256) void mgffn1(
    const bf16* __restrict__ An, int Mn,
    const bf16* __restrict__ Ae, int Me,
    const bf16* __restrict__ nBt, const void* __restrict__ nbias, bf16* __restrict__ Cn,
    const bf16* __restrict__ eBt, const void* __restrict__ ebias, bf16* __restrict__ Ce,
    int nby, const int* __restrict__ dflag)
{
    const bool isb = (*dflag != 0);
    __shared__ __align__(16) bf16 Al[128 * 64];
    __shared__ __align__(16) bf16 Bl[128 * 64];
    __shared__ float biasl[128];

    const int tid = threadIdx.x;
    const int lane = tid & 63, wave = tid >> 6;
    const int l15 = lane & 15, g = lane >> 4;
    const int t4 = l15 & 3, qd = l15 >> 2;
    const int wr = wave >> 1, wc = wave & 1;

    const int nwgx = gridDim.x;   // 8
    int wg = xcd_swz(blockIdx.y * nwgx + blockIdx.x, nwgx * gridDim.y);
    const int by = wg / nwgx, bx = wg % nwgx;
    const bool nodeb = (by < nby);
    const int rb = (nodeb ? by : (by - nby)) * 128;
    const int cb = bx * 128;
    const int M = nodeb ? Mn : Me;
    const bf16* A = nodeb ? An : Ae;
    const bf16* Bt = nodeb ? nBt : eBt;
    const void* bias = nodeb ? nbias : ebias;
    bf16* C = nodeb ? Cn : Ce;

    if (tid < 128) biasl[tid] = ldx(bias, cb + tid, isb);

    const int sp = lane & 7, sr8 = lane >> 3;
    int rls[4]; long arows[4];
    #pragma unroll
    for (int j = 0; j < 4; j++) {
        const int rl = wave * 32 + j * 8 + sr8;
        rls[j] = rl;
        const int gm = rb + rl;
        arows[j] = (gm < M) ? gm : (M - 1);
    }

    float4v acc[4][4];
    #pragma unroll
    for (int i = 0; i < 4; i++)
        #pragma unroll
        for (int j = 0; j < 4; j++)
            acc[i][j] = (float4v){0.f, 0.f, 0.f, 0.f};

    for (int k0 = 0; k0 < 256; k0 += 64) {
        #pragma unroll
        for (int j = 0; j < 4; j++) {
            const int rl = rls[j];
            const int pp = sp ^ (rl & 7);
            gl16(A + arows[j] * 256 + k0 + pp * 8,              Al + rl * 64 + sp * 8);
            gl16(Bt + (size_t)(cb + rl) * 256 + k0 + pp * 8,    Bl + rl * 64 + sp * 8);
        }
        __syncthreads();
        #pragma unroll
        for (int ks = 0; ks < 2; ks++) {
            short8v av[4], bv[4];
            #pragma unroll
            for (int mi = 0; mi < 4; mi++) {
                const int row = wr * 64 + mi * 16 + l15;
                const int cp = (ks * 4 + g) ^ (row & 7);
                av[mi] = *reinterpret_cast<const short8v*>(&Al[row * 64 + cp * 8]);
            }
            #pragma unroll
            for (int ni = 0; ni < 4; ni++) {
                const int row = wc * 64 + ni * 16 + l15;
                const int cp = (ks * 4 + g) ^ (row & 7);
                bv[ni] = *reinterpret_cast<const short8v*>(&Bl[row * 64 + cp * 8]);
            }
            #pragma unroll
            for (int mi = 0; mi < 4; mi++)
                #pragma unroll
                for (int ni = 0; ni < 4; ni++)
                    acc[mi][ni] = __builtin_amdgcn_mfma_f32_16x16x32_bf16(
                        av[mi], bv[ni], acc[mi][ni], 0, 0, 0);
        }
        __syncthreads();
    }

    #pragma unroll
    for (int mi = 0; mi < 4; mi++) {
        const int grow = rb + wr * 64 + mi * 16 + g * 4 + t4;
        const bool ok = (grow < M);
        #pragma unroll
        for (int ni = 0; ni < 4; ni++) {
            float a[4];
            #pragma unroll
            for (int r = 0; r < 4; r++) a[r] = acc[mi][ni][r];
            quadT(a, t4);
            if (!ok) continue;
            const int ct = wc * 64 + ni * 16 + qd * 4;
            U4 o;
            #pragma unroll
            for (int u = 0; u < 4; u++) o.h[u] = f2b(fmaxf(a[u] + biasl[ct + u], 0.f));
            *reinterpret_cast<int2*>(&C[(size_t)grow * 1024 + cb + ct]) = o.v;
        }
    }
}

// ---------------------------------------------------------------------------
// mgffn2: merged node+edge FFN2(+bias+resid) -> LN -> dtype-flex out
// (verified r17).  512 thr, K=1024.
// ---------------------------------------------------------------------------
__global__ __launch_bounds__(512) void mgffn2(
    const bf16* __restrict__ An, int Mn,
    const bf16* __restrict__ Ae, int Me,
    const bf16* __restrict__ nBt, const void* __restrict__ nbias,
    const bf16* __restrict__ nresid, const void* __restrict__ nlng, const void* __restrict__ nlnb,
    long nobase,
    const bf16* __restrict__ eBt, const void* __restrict__ ebias,
    const bf16* __restrict__ eresid, const void* __restrict__ elng, const void* __restrict__ elnb,
    long eobase,
    void* __restrict__ outv,
    int nby, const int* __restrict__ dflag)
{
    const bool isb = (*dflag != 0);
    __shared__ __align__(16) bf16 Al[128 * 64];   // 16KB (Ps overlay)
    __shared__ __align__(16) bf16 Bl[256 * 64];   // 32KB (Mr/Rsd overlay)
    __shared__ float biasl[256];
    __shared__ float lngl[256];
    __shared__ float lnbl[256];

    const int tid = threadIdx.x;
    const int lane = tid & 63, wave = tid >> 6;
    const int l15 = lane & 15, g = lane >> 4;
    const int t4 = l15 & 3, qd = l15 >> 2;
    const int wr = wave >> 2, wc = wave & 3;   // 2 x 4 wave grid

    const int wg = xcd_swz(blockIdx.y, gridDim.y);
    const bool nodeb = (wg < nby);
    const int rb = (nodeb ? wg : (wg - nby)) * 128;
    const int M = nodeb ? Mn : Me;
    const bf16* A = nodeb ? An : Ae;
    const bf16* Bt = nodeb ? nBt : eBt;
    const void* bias = nodeb ? nbias : ebias;
    const bf16* resid = nodeb ? nresid : eresid;
    const void* lng = nodeb ? nlng : elng;
    const void* lnb = nodeb ? nlnb : elnb;
    const long obase = nodeb ? nobase : eobase;

    if (tid < 256) {
        biasl[tid] = ldx(bias, tid, isb);
        lngl[tid]  = ldx(lng,  tid, isb);
        lnbl[tid]  = ldx(lnb,  tid, isb);
    }

    const int sp = lane & 7, sr8 = lane >> 3;
    int rlA[2]; long arA[2];
    #pragma unroll
    for (int j = 0; j < 2; j++) {
        const int rl = wave * 16 + j * 8 + sr8;
        rlA[j] = rl;
        const int gm = rb + rl;
        arA[j] = (gm < M) ? gm : (M - 1);
    }
    int rlB[4];
    #pragma unroll
    for (int j = 0; j < 4; j++) rlB[j] = wave * 32 + j * 8 + sr8;

    float4v acc[4][4];
    #pragma unroll
    for (int i = 0; i < 4; i++)
        #pragma unroll
        for (int j = 0; j < 4; j++)
            acc[i][j] = (float4v){0.f, 0.f, 0.f, 0.f};

    for (int k0 = 0; k0 < 1024; k0 += 64) {
        #pragma unroll
        for (int j = 0; j < 2; j++) {
            const int pp = sp ^ (rlA[j] & 7);
            gl16(A + arA[j] * 1024 + k0 + pp * 8, Al + rlA[j] * 64 + sp * 8);
        }
        #pragma unroll
        for (int j = 0; j < 4; j++) {
            const int pp = sp ^ (rlB[j] & 7);
            gl16(Bt + (size_t)rlB[j] * 1024 + k0 + pp * 8, Bl + rlB[j] * 64 + sp * 8);
        }
        __syncthreads();
        #pragma unroll
        for (int ks = 0; ks < 2; ks++) {
            short8v av[4], bv[4];
            #pragma unroll
            for (int mi = 0; mi < 4; mi++) {
                const int row = wr * 64 + mi * 16 + l15;
                const int cp = (ks * 4 + g) ^ (row & 7);
                av[mi] = *reinterpret_cast<const short8v*>(&Al[row * 64 + cp * 8]);
            }
            #pragma unroll
            for (int ni = 0; ni < 4; ni++) {
                const int row = wc * 64 + ni * 16 + l15;
                const int cp = (ks * 4 + g) ^ (row & 7);
                bv[ni] = *reinterpret_cast<const short8v*>(&Bl[row * 64 + cp * 8]);
            }
            #pragma unroll
            for (int mi = 0; mi < 4; mi++)
                #pragma unroll
                for (int ni = 0; ni < 4; ni++)
                    acc[mi][ni] = __builtin_amdgcn_mfma_f32_16x16x32_bf16(
                        av[mi], bv[ni], acc[mi][ni], 0, 0, 0);
        }
        __syncthreads();
    }

    float s1[4] = {0.f,0.f,0.f,0.f}, s2[4] = {0.f,0.f,0.f,0.f};
    #pragma unroll
    for (int mi = 0; mi < 4; mi++) {
        const int grow = rb + wr * 64 + mi * 16 + g * 4 + t4;
        const bool ok = (grow < M);
        #pragma unroll
        for (int ni = 0; ni < 4; ni++) {
            float a[4];
            #pragma unroll
            for (int r = 0; r < 4; r++) a[r] = acc[mi][ni][r];
            quadT(a, t4);
            const int ct = wc * 64 + ni * 16 + qd * 4;
            U4 rr; rr.v = make_int2(0, 0);
            if (ok) rr.v = *reinterpret_cast<const int2*>(&resid[(size_t)grow * 256 + ct]);
            #pragma unroll
            for (int u = 0; u < 4; u++) {
                a[u] += biasl[ct + u] + b2f(rr.h[u]);
                s1[mi] += a[u];
                s2[mi] += a[u] * a[u];
                acc[mi][ni][u] = a[u];
            }
        }
    }
    float* Ps1 = (float*)Al;          // [16][128]
    float* Ps2 = Ps1 + 2048;
    #pragma unroll
    for (int mi = 0; mi < 4; mi++) {
        const int rowl = wr * 64 + mi * 16 + g * 4 + t4;
        Ps1[(wc * 4 + qd) * 128 + rowl] = s1[mi];
        Ps2[(wc * 4 + qd) * 128 + rowl] = s2[mi];
    }
    __syncthreads();
    float* Mr  = (float*)Bl;
    float* Rsd = Mr + 128;
    if (tid < 128) {
        float a1 = 0.f, a2 = 0.f;
        #pragma unroll
        for (int k = 0; k < 16; k++) { a1 += Ps1[k * 128 + tid]; a2 += Ps2[k * 128 + tid]; }
        const float mn = a1 * (1.f / 256.f);
        const float var = a2 * (1.f / 256.f) - mn * mn;
        Mr[tid] = mn;
        Rsd[tid] = rsqrtf(fmaxf(var, 0.f) + 1e-5f);
    }
    __syncthreads();
    #pragma unroll
    for (int mi = 0; mi < 4; mi++) {
        const int rowl = wr * 64 + mi * 16 + g * 4 + t4;
        const int grow = rb + rowl;
        if (grow >= M) continue;
        const float mn = Mr[rowl], rd = Rsd[rowl];
        #pragma unroll
        for (int ni = 0; ni < 4; ni++) {
            const int ct = wc * 64 + ni * 16 + qd * 4;
            float o[4];
            #pragma unroll
            for (int u = 0; u < 4; u++)
                o[u] = (acc[mi][ni][u] - mn) * rd * lngl[ct + u] + lnbl[ct + u];
            if (isb) {
                U4 ob;
                #pragma unroll
                for (int u = 0; u < 4; u++) ob.h[u] = f2b(o[u]);
                *reinterpret_cast<int2*>((bf16*)outv + obase + (size_t)grow * 256 + ct) = ob.v;
            } else {
                float4 f4 = make_float4(o[0], o[1], o[2], o[3]);
                *reinterpret_cast<float4*>((float*)outv + obase + (size_t)grow * 256 + ct) = f4;
            }
        }
    }
}

// ---------------------------------------------------------------------------
extern "C" void kernel_launch(void* const* d_in, const int* in_sizes, int n_in,
                              void* d_out, int out_size, void* d_ws, size_t ws_size,
                              hipStream_t stream)
{
    const void* x   = d_in[0];
    const void* lgx = d_in[1];
    const int* local_src = (const int*)d_in[3];
    const int* lg_src    = (const int*)d_in[5];
    const int* src_ids   = (const int*)d_in[7];
    const int* dst_ids   = (const int*)d_in[8];

    const void *nWq = d_in[9],  *nbq = d_in[10], *nWk = d_in[11], *nWv = d_in[12],
               *nWo = d_in[13], *nbo = d_in[14], *nln1g = d_in[15], *nln1b = d_in[16],
               *nW1 = d_in[17], *nb1 = d_in[18], *nW2 = d_in[19], *nb2 = d_in[20],
               *nln2g = d_in[21], *nln2b = d_in[22];
    const void *eWq = d_in[23], *ebq = d_in[24], *eWk = d_in[25], *eWv = d_in[26],
               *eWo = d_in[27], *ebo = d_in[28], *eln1g = d_in[29], *eln1b = d_in[30],
               *eW1 = d_in[31], *eb1 = d_in[32], *eW2 = d_in[33], *eb2 = d_in[34],
               *eln2g = d_in[35], *eln2b = d_in[36];

    const dim3 blk(256);
    const dim3 blk2(512);

    // ===== ws layout (elements, bf16).  FE overlays [KVE..OE) which is dead
    // by the time mgffn1 runs (KVE/QE/QKVN dead after mgattn; OE after mgwoln).
    // fixed total = 545.9 MB < ~696 MB measured (r4/r5/r7).
    int* dflag = (int*)d_ws;
    detect_dtype<<<1, 64, 0, stream>>>((const unsigned short*)x, dflag);

    bf16* pk = (bf16*)((char*)d_ws + 256);
    bf16 *pnWq = pk,            *pnWk = pk + 65536,   *pnWv = pk + 131072,
         *pnWo = pk + 196608,   *peWq = pk + 262144,  *peWk = pk + 327680,
         *peWv = pk + 393216,   *peWo = pk + 458752,
         *pnW1 = pk + 524288,   *pnW2 = pk + 786432,
         *peW1 = pk + 1048576,  *peW2 = pk + 1310720;
    bf16* x16   = pk + 1572864;                        //  2,560,000 elems
    bf16* lgx16 = x16 + 2560000;                       // 40,960,000
    bf16* KVE   = lgx16 + 40960000;                    // 81,920,000  (overlay start)
    bf16* QE    = KVE + 81920000;                      // 40,960,000
    bf16* QKVN  = QE + 40960000;                       //  7,680,000
    bf16* OE    = QKVN + 7680000;                      // 40,960,000  (overlay end: 171.52M elems)
    bf16* ON    = OE + 40960000;                       //  2,560,000
    bf16* HN    = ON + 2560000;                        //  2,560,000
    bf16* FN    = HN + 2560000;                        // 10,240,000
    bf16* HE    = FN + 10240000;                       // 40,960,000
    bf16* FE    = KVE;                                 // overlay: needs 163,840,000 <= 171,520,000

    cvt_both<<<21250, blk, 0, stream>>>(x, lgx, x16, lgx16, dflag);

    PackArgs pa;
    pa.src[0] = nWq; pa.src[1] = nWk; pa.src[2] = nWv; pa.src[3] = nWo;
    pa.src[4] = eWq; pa.src[5] = eWk; pa.src[6] = eWv; pa.src[7] = eWo;
    pa.src[8] = nW1; pa.src[9] = nW2; pa.src[10] = eW1; pa.src[11] = eW2;
    pa.dst[0] = pnWq; pa.dst[1] = pnWk; pa.dst[2] = pnWv; pa.dst[3] = pnWo;
    pa.dst[4] = peWq; pa.dst[5] = peWk; pa.dst[6] = peWv; pa.dst[7] = peWo;
    pa.dst[8] = pnW1; pa.dst[9] = pnW2; pa.dst[10] = peW1; pa.dst[11] = peW2;
    pack_all<<<6144, blk, 0, stream>>>(pa, dflag);

    const int nby = (N_NODES + 127) / 128;   // 79
    const int eby = (E_EDGES + 127) / 128;   // 1250

    // stage 1: merged QKV (node + edge)
    mgqkv<<<dim3(6, nby + eby), blk, 0, stream>>>(
        x16, N_NODES, lgx16, E_EDGES,
        pnWq, pnWk, pnWv, nbq,
        peWq, peWk, peWv, ebq,
        x16, src_ids, dst_ids,
        QKVN, QE, KVE, nby, dflag);

    // stage 2: merged attention
    const int nab = (N_NODES + 3) / 4;        // 2500
    const int eab = (E_EDGES + 3) / 4;        // 40000
    mgattn<<<nab + eab, blk, 0, stream>>>(
        QKVN, local_src, lgx16, ON, QE, KVE, lg_src, OE, nab);

    // stage 3: merged Wo + LN1
    mgwoln<<<dim3(1, nby + eby), blk2, 0, stream>>>(
        ON, N_NODES, OE, E_EDGES,
        pnWo, nbo, x16, nln1g, nln1b, HN,
        peWo, ebo, lgx16, eln1g, eln1b, HE,
        nby, dflag);

    // stage 4: merged FFN1 (full E, FE overlays dead buffers)
    mgffn1<<<dim3(8, nby + eby), blk, 0, stream>>>(
        HN, N_NODES, HE, E_EDGES,
        pnW1, nb1, FN,
        peW1, eb1, FE,
        nby, dflag);

    // stage 5: merged FFN2 + LN2 -> out
    mgffn2<<<dim3(1, nby + eby), blk2, 0, stream>>>(
        FN, N_NODES, FE, E_EDGES,
        pnW2, nb2, HN, nln2g, nln2b, 0L,
        peW2, eb2, HE, eln2g, eln2b, (long)N_NODES * 256,
        d_out, nby, dflag);
}